// Round 17
// baseline (1182.277 us; speedup 1.0000x reference)
//
#include <hip/hip_runtime.h>
#include <hip/hip_bf16.h>
#include <cstdint>
#include <cstddef>

#define NFEAT 512
#define H2 256
#define H3 256
#define H4 128
#define NCLASS 16

typedef __attribute__((ext_vector_type(8))) short short8;
typedef __attribute__((ext_vector_type(4))) float f32x4;
typedef __attribute__((ext_vector_type(4))) unsigned short ushort4v;
typedef __attribute__((ext_vector_type(4))) _Float16 half4v;
typedef __attribute__((ext_vector_type(2))) _Float16 half2v;

#define AS1 __attribute__((address_space(1)))
#define AS3 __attribute__((address_space(3)))

__device__ inline unsigned short f2bf_rne(float x) {
    unsigned int u = __builtin_bit_cast(unsigned int, x);
    unsigned int r = (u + 0x7FFFu + ((u >> 16) & 1u)) >> 16;
    return (unsigned short)r;
}
__device__ inline float bf2f(unsigned short h) {
    return __builtin_bit_cast(float, (unsigned int)h << 16);
}

template <int VM> __device__ __forceinline__ void vm_wait() {
    asm volatile("s_waitcnt vmcnt(%0)" :: "n"(VM) : "memory");
}
__device__ __forceinline__ void lgkm0() {
    asm volatile("s_waitcnt lgkmcnt(0)" ::: "memory");
}

// ---------------- CSR build ----------------
__global__ void k_hist(const int* __restrict__ er, int* __restrict__ cnt, int E) {
    for (int e = blockIdx.x * blockDim.x + threadIdx.x; e < E; e += gridDim.x * blockDim.x)
        atomicAdd(&cnt[er[e]], 1);
}

__global__ void k_scan1(const int* __restrict__ cnt, int* __restrict__ ex,
                        int* __restrict__ bsum, int n) {
    __shared__ int s[256];
    int i = blockIdx.x * 256 + threadIdx.x;
    int v = (i < n) ? cnt[i] : 0;
    s[threadIdx.x] = v;
    __syncthreads();
    #pragma unroll
    for (int off = 1; off < 256; off <<= 1) {
        int t = (threadIdx.x >= (unsigned)off) ? s[threadIdx.x - off] : 0;
        __syncthreads();
        s[threadIdx.x] += t;
        __syncthreads();
    }
    if (i < n) ex[i] = s[threadIdx.x] - v;
    if (threadIdx.x == 255) bsum[blockIdx.x] = s[255];
}

__global__ void k_scan2(int* __restrict__ bsum, int nb) {
    __shared__ int s[512];
    int v = ((int)threadIdx.x < nb) ? bsum[threadIdx.x] : 0;
    s[threadIdx.x] = v;
    __syncthreads();
    #pragma unroll
    for (int off = 1; off < 512; off <<= 1) {
        int t = (threadIdx.x >= (unsigned)off) ? s[threadIdx.x - off] : 0;
        __syncthreads();
        s[threadIdx.x] += t;
        __syncthreads();
    }
    if ((int)threadIdx.x < nb) bsum[threadIdx.x] = s[threadIdx.x] - v;
}

__global__ void k_scan3(int* __restrict__ rp, int* __restrict__ ofs,
                        const int* __restrict__ bsum, const int* __restrict__ cnt,
                        int n) {
    int i = blockIdx.x * 256 + threadIdx.x;
    if (i < n) {
        int v = rp[i] + bsum[blockIdx.x];
        rp[i] = v;
        ofs[i] = v;
        if (i == n - 1) rp[n] = v + cnt[i];
    }
}

// bofs[b] = rp[b*256] (bucket frontier init)
__global__ void k_binit(const int* __restrict__ rp, int* __restrict__ bofs, int nbk) {
    int i = blockIdx.x * 256 + threadIdx.x;
    if (i < nbk) bofs[i] = rp[i * 256];
}

// phase 1: edges -> bucket regions of tmp (monotone frontier writes -> full lines).
// tmp.x = col | (rowlocal<<17), tmp.y = val bits. col < 2^17, rowlocal < 256.
__global__ void k_bucket(const int* __restrict__ er, const int* __restrict__ ec,
                         const float* __restrict__ ev, int* __restrict__ bofs,
                         int2* __restrict__ tmp, int E) {
    for (int e = blockIdx.x * blockDim.x + threadIdx.x; e < E; e += gridDim.x * blockDim.x) {
        int r = er[e];
        int p = atomicAdd(&bofs[r >> 8], 1);
        tmp[p] = make_int2(ec[e] | ((r & 255) << 17), __builtin_bit_cast(int, ev[e]));
    }
}

// phase 2: one block per bucket; sequential read, write within bucket's CSR window.
__global__ __launch_bounds__(256)
void k_place(const int2* __restrict__ tmp, const int* __restrict__ rp,
             int* __restrict__ ofs, int2* __restrict__ ev2, int N) {
    const int b = blockIdx.x;
    const int row0 = b * 256;
    const int beg = rp[row0];
    const int end = rp[min(row0 + 256, N)];
    for (int e = beg + threadIdx.x; e < end; e += 256) {
        int2 t = tmp[e];
        int row = row0 + ((t.x >> 17) & 255);
        int col = t.x & 0x1FFFF;
        int pos = atomicAdd(&ofs[row], 1);
        ev2[pos] = make_int2(col, t.y);
    }
}

// ---------------- weight pack: W[K][M] fp32 -> fragment-major bf16 hi/lo ----------------
__global__ __launch_bounds__(256)
void k_packb(const float* __restrict__ W, unsigned short* __restrict__ hi,
             unsigned short* __restrict__ lo, int K, int M) {
    int idx = blockIdx.x * 256 + threadIdx.x;
    int NT = K >> 5;
    int total = (M >> 4) * NT * 64;
    if (idx >= total) return;
    int l = idx & 63;
    int t = (idx >> 6) % NT;
    int cg = idx / (NT << 6);
    int col = cg * 16 + (l & 15);
    int k0 = t * 32 + (l >> 4) * 8;
    short8 h8, l8;
    #pragma unroll
    for (int j = 0; j < 8; ++j) {
        float x = W[(size_t)(k0 + j) * M + col];
        unsigned short h = f2bf_rne(x);
        h8[j] = (short)h;
        l8[j] = (short)f2bf_rne(x - bf2f(h));
    }
    *(short8*)&hi[(size_t)idx * 8] = h8;
    *(short8*)&lo[(size_t)idx * 8] = l8;
}

// ---------------- GEMM1 (counted-vmcnt, 3-buf): C16[N,256] = fp16(X[N,512] @ W1) ----------------
__global__ __launch_bounds__(256, 3)
void k_gemm1c(const float* __restrict__ X, const unsigned short* __restrict__ Bh,
              const unsigned short* __restrict__ Bl, _Float16* __restrict__ C16, const int N) {
    constexpr int K = 512, M = 256, NT = K / 32;
    __shared__ char smem[24576];
    float* sX = (float*)smem;
    const int tid = threadIdx.x;
    const int lane = tid & 63;
    const int w = tid >> 6;
    const int lm = lane & 15, lk = lane >> 4;
    const int row0 = blockIdx.x * 64;
    const int col0 = w * 64;

    const int kseg = (lane & 7) ^ ((lane >> 3) & 7);
    const int r0 = min(row0 + w * 16 + (lane >> 3), N - 1);
    const int r1 = min(row0 + w * 16 + 8 + (lane >> 3), N - 1);
    const size_t ga0 = (size_t)r0 * K + kseg * 4;
    const size_t ga1 = (size_t)r1 * K + kseg * 4;

    const unsigned short* bfh = Bh + ((size_t)(w * 4) * NT) * 512 + lane * 8;
    const unsigned short* bfl = Bl + ((size_t)(w * 4) * NT) * 512 + lane * 8;

    f32x4 acc[4][4];
    #pragma unroll
    for (int i = 0; i < 4; ++i)
        #pragma unroll
        for (int j = 0; j < 4; ++j) acc[i][j] = (f32x4){0.f, 0.f, 0.f, 0.f};

    auto stage = [&](int bi, int kk) {
        __builtin_amdgcn_global_load_lds((const AS1 void*)(X + ga0 + kk),
                                         (AS3 void*)(sX + bi * 2048 + w * 512), 16, 0, 0);
        __builtin_amdgcn_global_load_lds((const AS1 void*)(X + ga1 + kk),
                                         (AS3 void*)(sX + bi * 2048 + w * 512 + 256), 16, 0, 0);
    };

    stage(0, 0); stage(1, 32); stage(2, 64);

    short8 bhf[4], blf[4];
    #pragma unroll
    for (int nf = 0; nf < 4; ++nf) {
        const size_t o = (size_t)nf * NT * 512;
        bhf[nf] = *(const short8*)(bfh + o);
        blf[nf] = *(const short8*)(bfl + o);
    }

    const int u0 = ((2 * lk) ^ (lm & 7)) * 4;
    const int u1 = ((2 * lk + 1) ^ (lm & 7)) * 4;
    int bi = 0;

#define G1_BODY(T, VM)                                                          \
    {                                                                           \
        vm_wait<VM>();                                                          \
        __builtin_amdgcn_s_barrier();                                           \
        __builtin_amdgcn_sched_barrier(0);                                      \
        short8 bhn[4], bln[4];                                                  \
        _Pragma("unroll")                                                       \
        for (int nf = 0; nf < 4; ++nf) { bhn[nf] = bhf[nf]; bln[nf] = blf[nf]; }\
        if ((T) + 1 < NT) {                                                     \
            _Pragma("unroll")                                                   \
            for (int nf = 0; nf < 4; ++nf) {                                    \
                const size_t o = ((size_t)nf * NT + (T) + 1) * 512;             \
                bhn[nf] = *(const short8*)(bfh + o);                            \
                bln[nf] = *(const short8*)(bfl + o);                            \
            }                                                                   \
        }                                                                       \
        __builtin_amdgcn_sched_barrier(0);                                      \
        _Pragma("unroll")                                                       \
        for (int mf = 0; mf < 4; ++mf) {                                        \
            const float* ab = sX + bi * 2048 + (mf * 16 + lm) * 32;             \
            f32x4 p0 = *(const f32x4*)(ab + u0);                                \
            f32x4 p1 = *(const f32x4*)(ab + u1);                                \
            float vv[8] = {p0.x, p0.y, p0.z, p0.w, p1.x, p1.y, p1.z, p1.w};     \
            short8 ah, al;                                                      \
            _Pragma("unroll")                                                   \
            for (int j = 0; j < 8; ++j) {                                       \
                unsigned int uu = __builtin_bit_cast(unsigned int, vv[j]);      \
                ah[j] = (short)(uu >> 16);                                      \
                float hi_ = __builtin_bit_cast(float, uu & 0xFFFF0000u);        \
                al[j] = (short)f2bf_rne(vv[j] - hi_);                           \
            }                                                                   \
            _Pragma("unroll")                                                   \
            for (int nf = 0; nf < 4; ++nf) {                                    \
                acc[mf][nf] = __builtin_amdgcn_mfma_f32_16x16x32_bf16(ah, bhf[nf], acc[mf][nf], 0, 0, 0); \
                acc[mf][nf] = __builtin_amdgcn_mfma_f32_16x16x32_bf16(ah, blf[nf], acc[mf][nf], 0, 0, 0); \
                acc[mf][nf] = __builtin_amdgcn_mfma_f32_16x16x32_bf16(al, bhf[nf], acc[mf][nf], 0, 0, 0); \
            }                                                                   \
        }                                                                       \
        lgkm0();                                                                \
        __builtin_amdgcn_sched_barrier(0);                                      \
        __builtin_amdgcn_s_barrier();                                           \
        if ((T) + 3 < NT) stage(bi, ((T) + 3) * 32);                            \
        _Pragma("unroll")                                                       \
        for (int nf = 0; nf < 4; ++nf) { bhf[nf] = bhn[nf]; blf[nf] = bln[nf]; }\
        bi = bi + 1; if (bi == 3) bi = 0;                                       \
    }

    for (int t = 0; t < NT - 2; ++t) G1_BODY(t, 12);
    G1_BODY(NT - 2, 10);
    G1_BODY(NT - 1, 8);
#undef G1_BODY

    float* sc = (float*)smem;
    #pragma unroll
    for (int mf = 0; mf < 4; ++mf) {
        __syncthreads();
        #pragma unroll
        for (int nf = 0; nf < 4; ++nf)
            #pragma unroll
            for (int r = 0; r < 4; ++r) {
                const int rl = lk * 4 + r;
                const int col = col0 + nf * 16 + lm;
                sc[rl * M + (col ^ (lk << 3))] = acc[mf][nf][r];
            }
        __syncthreads();
        #pragma unroll
        for (int i = 0; i < 4; ++i) {
            const int idx = i * 256 + tid;
            const int rl = idx >> 6, u = idx & 63;
            const int grow = row0 + mf * 16 + rl;
            if (grow < N) {
                f32x4 v = *(const f32x4*)&sc[rl * M + ((u * 4) ^ (((rl >> 2) & 3) << 3))];
                half4v h;
                h[0] = (_Float16)v[0]; h[1] = (_Float16)v[1];
                h[2] = (_Float16)v[2]; h[3] = (_Float16)v[3];
                *(half4v*)&C16[(size_t)grow * M + u * 4] = h;
            }
        }
    }
}

// ---------------- GEMM (A pre-split bf16 h/l), counted-vmcnt 3-buf, fp16 out ----------------
template <int K, int NFW>
__global__ __launch_bounds__(256, 3)
void k_gemm_btc(const unsigned short* __restrict__ Ah, const unsigned short* __restrict__ Al,
                const unsigned short* __restrict__ Bh, const unsigned short* __restrict__ Bl,
                _Float16* __restrict__ C16, const int N) {
    constexpr int M = 64 * NFW;
    constexpr int NT = K / 32;
    constexpr int UPR = 16 * NFW;
    __shared__ char smem[24576];
    unsigned short* sAh = (unsigned short*)smem;          // [3][2048]
    unsigned short* sAl = sAh + 6144;                     // [3][2048]
    const int tid = threadIdx.x;
    const int lane = tid & 63;
    const int w = tid >> 6;
    const int lm = lane & 15, lk = lane >> 4;
    const int row0 = blockIdx.x * 64;
    const int col0 = w * (16 * NFW);

    const int kseg = (lane & 3) ^ ((lane >> 2) & 3);
    const int gr = min(row0 + w * 16 + (lane >> 2), N - 1);
    const size_t ga = (size_t)gr * K + kseg * 8;

    const int aoff = lm * 32 + ((lk ^ (lm & 3)) * 8);

    const unsigned short* bfh = Bh + ((size_t)(w * NFW) * NT) * 512 + lane * 8;
    const unsigned short* bfl = Bl + ((size_t)(w * NFW) * NT) * 512 + lane * 8;

    f32x4 acc[4][NFW];
    #pragma unroll
    for (int i = 0; i < 4; ++i)
        #pragma unroll
        for (int j = 0; j < NFW; ++j) acc[i][j] = (f32x4){0.f, 0.f, 0.f, 0.f};

    auto stage = [&](int bi, int kk) {
        __builtin_amdgcn_global_load_lds((const AS1 void*)(Ah + ga + kk),
                                         (AS3 void*)(sAh + bi * 2048 + w * 512), 16, 0, 0);
        __builtin_amdgcn_global_load_lds((const AS1 void*)(Al + ga + kk),
                                         (AS3 void*)(sAl + bi * 2048 + w * 512), 16, 0, 0);
    };

    stage(0, 0); stage(1, 32); stage(2, 64);

    short8 bhf[NFW], blf[NFW];
    #pragma unroll
    for (int nf = 0; nf < NFW; ++nf) {
        const size_t o = (size_t)nf * NT * 512;
        bhf[nf] = *(const short8*)(bfh + o);
        blf[nf] = *(const short8*)(bfl + o);
    }

    int bi = 0;

#define GBT_BODY(T, VM)                                                         \
    {                                                                           \
        vm_wait<VM>();                                                          \
        __builtin_amdgcn_s_barrier();                                           \
        __builtin_amdgcn_sched_barrier(0);                                      \
        short8 bhn[NFW], bln[NFW];                                              \
        _Pragma("unroll")                                                       \
        for (int nf = 0; nf < NFW; ++nf) { bhn[nf] = bhf[nf]; bln[nf] = blf[nf]; } \
        if ((T) + 1 < NT) {                                                     \
            _Pragma("unroll")                                                   \
            for (int nf = 0; nf < NFW; ++nf) {                                  \
                const size_t o = ((size_t)nf * NT + (T) + 1) * 512;             \
                bhn[nf] = *(const short8*)(bfh + o);                            \
                bln[nf] = *(const short8*)(bfl + o);                            \
            }                                                                   \
        }                                                                       \
        __builtin_amdgcn_sched_barrier(0);                                      \
        _Pragma("unroll")                                                       \
        for (int mf = 0; mf < 4; ++mf) {                                        \
            short8 ah = *(const short8*)&sAh[bi * 2048 + aoff + mf * 512];      \
            short8 al = *(const short8*)&sAl[bi * 2048 + aoff + mf * 512];      \
            _Pragma("unroll")                                                   \
            for (int nf = 0; nf < NFW; ++nf) {                                  \
                acc[mf][nf] = __builtin_amdgcn_mfma_f32_16x16x32_bf16(ah, bhf[nf], acc[mf][nf], 0, 0, 0); \
                acc[mf][nf] = __builtin_amdgcn_mfma_f32_16x16x32_bf16(ah, blf[nf], acc[mf][nf], 0, 0, 0); \
                acc[mf][nf] = __builtin_amdgcn_mfma_f32_16x16x32_bf16(al, bhf[nf], acc[mf][nf], 0, 0, 0); \
            }                                                                   \
        }                                                                       \
        lgkm0();                                                                \
        __builtin_amdgcn_sched_barrier(0);                                      \
        __builtin_amdgcn_s_barrier();                                           \
        if ((T) + 3 < NT) stage(bi, ((T) + 3) * 32);                            \
        _Pragma("unroll")                                                       \
        for (int nf = 0; nf < NFW; ++nf) { bhf[nf] = bhn[nf]; blf[nf] = bln[nf]; } \
        bi = bi + 1; if (bi == 3) bi = 0;                                       \
    }

    for (int t = 0; t < NT - 2; ++t) GBT_BODY(t, 2 * NFW + 4);
    GBT_BODY(NT - 2, 2 * NFW + 2);
    GBT_BODY(NT - 1, 2 * NFW);
#undef GBT_BODY

    float* sc = (float*)smem;
    #pragma unroll
    for (int mf = 0; mf < 4; ++mf) {
        __syncthreads();
        #pragma unroll
        for (int nf = 0; nf < NFW; ++nf)
            #pragma unroll
            for (int r = 0; r < 4; ++r) {
                const int rl = lk * 4 + r;
                const int col = col0 + nf * 16 + lm;
                sc[rl * M + (col ^ (lk << 3))] = acc[mf][nf][r];
            }
        __syncthreads();
        #pragma unroll
        for (int i = 0; i < (16 * UPR) / 256; ++i) {
            const int idx = i * 256 + tid;
            const int rl = idx / UPR, u = idx % UPR;
            const int grow = row0 + mf * 16 + rl;
            if (grow < N) {
                f32x4 v = *(const f32x4*)&sc[rl * M + ((u * 4) ^ (((rl >> 2) & 3) << 3))];
                half4v h;
                h[0] = (_Float16)v[0]; h[1] = (_Float16)v[1];
                h[2] = (_Float16)v[2]; h[3] = (_Float16)v[3];
                *(half4v*)&C16[(size_t)grow * M + u * 4] = h;
            }
        }
    }
}

// ---------------- SpMM on fp16 input (F=256), wave-per-row, fused bias+relu+split ----------------
__global__ __launch_bounds__(256)
void k_spmm256f(const int* __restrict__ rp, const int2* __restrict__ ev2,
                const _Float16* __restrict__ in16, const float* __restrict__ bias,
                unsigned short* __restrict__ oh, unsigned short* __restrict__ ol, int N) {
    const int lane = threadIdx.x & 63;
    int r = __builtin_amdgcn_readfirstlane(blockIdx.x * 4 + (threadIdx.x >> 6));
    if (r >= N) return;
    const int e0 = __builtin_amdgcn_readfirstlane(rp[r]);
    const int e1 = __builtin_amdgcn_readfirstlane(rp[r + 1]);
    f32x4 acc = {0.f, 0.f, 0.f, 0.f};
    const _Float16* base = in16 + lane * 4;

    #pragma unroll 4
    for (int e = e0; e < e1; ++e) {
        int2 p = ev2[e];
        half4v hv = *(const half4v*)(base + (size_t)p.x * 256);
        float val = __builtin_bit_cast(float, p.y);
        acc[0] = fmaf(val, (float)hv[0], acc[0]);
        acc[1] = fmaf(val, (float)hv[1], acc[1]);
        acc[2] = fmaf(val, (float)hv[2], acc[2]);
        acc[3] = fmaf(val, (float)hv[3], acc[3]);
    }

    f32x4 bv = *(const f32x4*)&bias[lane * 4];
    ushort4v h, l;
    #pragma unroll
    for (int j = 0; j < 4; ++j) {
        float o = fmaxf(acc[j] + bv[j], 0.f);
        unsigned short hh = f2bf_rne(o);
        h[j] = hh;
        l[j] = f2bf_rne(o - bf2f(hh));
    }
    *(ushort4v*)&oh[(size_t)r * 256 + lane * 4] = h;
    *(ushort4v*)&ol[(size_t)r * 256 + lane * 4] = l;
}

// ---------------- SpMM F=128 on fp16 input + fused bias/relu + final dense ----------------
__global__ __launch_bounds__(256)
void k_spmm128f(const int* __restrict__ rp, const int2* __restrict__ ev2,
                const _Float16* __restrict__ in16, const float* __restrict__ b3,
                const float* __restrict__ Wd, const float* __restrict__ bd,
                float* __restrict__ out, int N) {
    __shared__ float Ws[H4 * NCLASS];
    __shared__ float hrow[4][H4];
    {
        int i = threadIdx.x * 8;
        *(f32x4*)&Ws[i] = *(const f32x4*)&Wd[i];
        *(f32x4*)&Ws[i + 4] = *(const f32x4*)&Wd[i + 4];
    }
    __syncthreads();

    const int lane = threadIdx.x & 63;
    const int w = threadIdx.x >> 6;
    int r = __builtin_amdgcn_readfirstlane(blockIdx.x * 4 + w);
    if (r >= N) return;
    const int e0 = __builtin_amdgcn_readfirstlane(rp[r]);
    const int e1 = __builtin_amdgcn_readfirstlane(rp[r + 1]);
    float a0 = 0.f, a1 = 0.f;
    const _Float16* base = in16 + lane * 2;

    #pragma unroll 4
    for (int e = e0; e < e1; ++e) {
        int2 p = ev2[e];
        half2v hv = *(const half2v*)(base + (size_t)p.x * 128);
        float v = __builtin_bit_cast(float, p.y);
        a0 = fmaf(v, (float)hv[0], a0);
        a1 = fmaf(v, (float)hv[1], a1);
    }

    float2 hb;
    hb.x = fmaxf(a0 + b3[lane * 2 + 0], 0.f);
    hb.y = fmaxf(a1 + b3[lane * 2 + 1], 0.f);
    *(float2*)&hrow[w][lane * 2] = hb;

    const int c = lane & 15, q = lane >> 4;
    float s = 0.f;
    #pragma unroll
    for (int k = q * 32; k < q * 32 + 32; ++k)
        s = fmaf(hrow[w][k], Ws[k * NCLASS + c], s);
    s += __shfl_xor(s, 16);
    s += __shfl_xor(s, 32);
    if (lane < 16) out[(size_t)r * NCLASS + lane] = s + bd[lane];
}

extern "C" void kernel_launch(void* const* d_in, const int* in_sizes, int n_in,
                              void* d_out, int out_size, void* d_ws, size_t ws_size,
                              hipStream_t stream) {
    const float* x  = (const float*)d_in[0];
    const int*   er = (const int*)d_in[1];
    const int*   ec = (const int*)d_in[2];
    const float* ev = (const float*)d_in[3];
    const float* W1 = (const float*)d_in[4];
    const float* b1 = (const float*)d_in[5];
    const float* W2 = (const float*)d_in[6];
    const float* b2 = (const float*)d_in[7];
    const float* W3 = (const float*)d_in[8];
    const float* b3 = (const float*)d_in[9];
    const float* Wd = (const float*)d_in[10];
    const float* bd = (const float*)d_in[11];
    float* out = (float*)d_out;

    const int N = in_sizes[0] / NFEAT;
    const int E = in_sizes[1];

    char* w = (char*)d_ws;
    auto alloc = [&](size_t bytes) { char* p = w; w += (bytes + 255) & ~(size_t)255; return p; };
    _Float16* C16 = (_Float16*)alloc((size_t)N * 256 * 2);
    unsigned short* hh = (unsigned short*)alloc((size_t)N * 256 * 2);
    unsigned short* hl = (unsigned short*)alloc((size_t)N * 256 * 2);
    int* cnt  = (int*)alloc((size_t)N * 4);
    int* rp   = (int*)alloc((size_t)(N + 1) * 4);
    int* ofs  = (int*)alloc((size_t)N * 4);
    int2* ev2 = (int2*)alloc((size_t)E * 8);
    int2* tmp = (int2*)alloc((size_t)E * 8);
    int* bsum = (int*)alloc(4096);
    int* bofs = (int*)alloc(((size_t)N / 256 + 2) * 4);
    unsigned short* W1h = (unsigned short*)alloc((size_t)NFEAT * H2 * 2);
    unsigned short* W1l = (unsigned short*)alloc((size_t)NFEAT * H2 * 2);
    unsigned short* W2h = (unsigned short*)alloc((size_t)H2 * H3 * 2);
    unsigned short* W2l = (unsigned short*)alloc((size_t)H2 * H3 * 2);
    unsigned short* W3h = (unsigned short*)alloc((size_t)H3 * H4 * 2);
    unsigned short* W3l = (unsigned short*)alloc((size_t)H3 * H4 * 2);

    const int nb = (N + 255) / 256;   // scan blocks == bucket count

    hipMemsetAsync(cnt, 0, (size_t)N * 4, stream);
    k_hist<<<1024, 256, 0, stream>>>(er, cnt, E);
    k_scan1<<<nb, 256, 0, stream>>>(cnt, rp, bsum, N);
    k_scan2<<<1, 512, 0, stream>>>(bsum, nb);
    k_scan3<<<nb, 256, 0, stream>>>(rp, ofs, bsum, cnt, N);
    k_binit<<<(nb + 255) / 256, 256, 0, stream>>>(rp, bofs, nb);
    k_bucket<<<2048, 256, 0, stream>>>(er, ec, ev, bofs, tmp, E);
    k_place<<<nb, 256, 0, stream>>>(tmp, rp, ofs, ev2, N);

    k_packb<<<(NFEAT * H2 / 8 + 255) / 256, 256, 0, stream>>>(W1, W1h, W1l, NFEAT, H2);
    k_packb<<<(H2 * H3 / 8 + 255) / 256, 256, 0, stream>>>(W2, W2h, W2l, H2, H3);
    k_packb<<<(H3 * H4 / 8 + 255) / 256, 256, 0, stream>>>(W3, W3h, W3l, H3, H4);

    const int rgrid = (N + 63) / 64;
    const int sgrid = (N + 3) / 4;

    k_gemm1c<<<rgrid, 256, 0, stream>>>(x, W1h, W1l, C16, N);
    k_spmm256f<<<sgrid, 256, 0, stream>>>(rp, ev2, C16, b1, hh, hl, N);

    k_gemm_btc<H2, 4><<<rgrid, 256, 0, stream>>>(hh, hl, W2h, W2l, C16, N);
    k_spmm256f<<<sgrid, 256, 0, stream>>>(rp, ev2, C16, b2, hh, hl, N);

    k_gemm_btc<H3, 2><<<rgrid, 256, 0, stream>>>(hh, hl, W3h, W3l, C16, N);
    k_spmm128f<<<sgrid, 256, 0, stream>>>(rp, ev2, C16, b3, Wd, bd, out, N);
}

// Round 18
// 758.432 us; speedup vs baseline: 1.5588x; 1.5588x over previous
//
#include <hip/hip_runtime.h>
#include <hip/hip_bf16.h>
#include <cstdint>
#include <cstddef>

#define NFEAT 512
#define H2 256
#define H3 256
#define H4 128
#define NCLASS 16

typedef __attribute__((ext_vector_type(8))) short short8;
typedef __attribute__((ext_vector_type(4))) float f32x4;
typedef __attribute__((ext_vector_type(4))) unsigned short ushort4v;
typedef __attribute__((ext_vector_type(4))) _Float16 half4v;
typedef __attribute__((ext_vector_type(2))) _Float16 half2v;

#define AS1 __attribute__((address_space(1)))
#define AS3 __attribute__((address_space(3)))

__device__ inline unsigned short f2bf_rne(float x) {
    unsigned int u = __builtin_bit_cast(unsigned int, x);
    unsigned int r = (u + 0x7FFFu + ((u >> 16) & 1u)) >> 16;
    return (unsigned short)r;
}
__device__ inline float bf2f(unsigned short h) {
    return __builtin_bit_cast(float, (unsigned int)h << 16);
}

template <int VM> __device__ __forceinline__ void vm_wait() {
    asm volatile("s_waitcnt vmcnt(%0)" :: "n"(VM) : "memory");
}
__device__ __forceinline__ void lgkm0() {
    asm volatile("s_waitcnt lgkmcnt(0)" ::: "memory");
}

// ---------------- CSR build ----------------
__global__ void k_hist(const int* __restrict__ er, int* __restrict__ cnt, int E) {
    for (int e = blockIdx.x * blockDim.x + threadIdx.x; e < E; e += gridDim.x * blockDim.x)
        atomicAdd(&cnt[er[e]], 1);
}

__global__ void k_scan1(const int* __restrict__ cnt, int* __restrict__ ex,
                        int* __restrict__ bsum, int n) {
    __shared__ int s[256];
    int i = blockIdx.x * 256 + threadIdx.x;
    int v = (i < n) ? cnt[i] : 0;
    s[threadIdx.x] = v;
    __syncthreads();
    #pragma unroll
    for (int off = 1; off < 256; off <<= 1) {
        int t = (threadIdx.x >= (unsigned)off) ? s[threadIdx.x - off] : 0;
        __syncthreads();
        s[threadIdx.x] += t;
        __syncthreads();
    }
    if (i < n) ex[i] = s[threadIdx.x] - v;
    if (threadIdx.x == 255) bsum[blockIdx.x] = s[255];
}

__global__ void k_scan2(int* __restrict__ bsum, int nb) {
    __shared__ int s[512];
    int v = ((int)threadIdx.x < nb) ? bsum[threadIdx.x] : 0;
    s[threadIdx.x] = v;
    __syncthreads();
    #pragma unroll
    for (int off = 1; off < 512; off <<= 1) {
        int t = (threadIdx.x >= (unsigned)off) ? s[threadIdx.x - off] : 0;
        __syncthreads();
        s[threadIdx.x] += t;
        __syncthreads();
    }
    if ((int)threadIdx.x < nb) bsum[threadIdx.x] = s[threadIdx.x] - v;
}

__global__ void k_scan3(int* __restrict__ rp, int* __restrict__ ofs,
                        const int* __restrict__ bsum, const int* __restrict__ cnt,
                        int n) {
    int i = blockIdx.x * 256 + threadIdx.x;
    if (i < n) {
        int v = rp[i] + bsum[blockIdx.x];
        rp[i] = v;
        ofs[i] = v;
        if (i == n - 1) rp[n] = v + cnt[i];
    }
}

// bofs[b*16] = rp[b*64] (bucket frontier init; one counter per 64B line)
__global__ void k_binit(const int* __restrict__ rp, int* __restrict__ bofs, int nbk) {
    int i = blockIdx.x * 256 + threadIdx.x;
    if (i < nbk) bofs[i * 16] = rp[i * 64];
}

// phase 1: edges -> 64-row bucket regions of tmp (monotone frontiers, padded counters).
// tmp.x = col | (rowlocal<<17), tmp.y = val bits. col < 2^17, rowlocal < 64.
__global__ void k_bucket(const int* __restrict__ er, const int* __restrict__ ec,
                         const float* __restrict__ ev, int* __restrict__ bofs,
                         int2* __restrict__ tmp, int E) {
    for (int e = blockIdx.x * blockDim.x + threadIdx.x; e < E; e += gridDim.x * blockDim.x) {
        int r = er[e];
        int p = atomicAdd(&bofs[(r >> 6) * 16], 1);
        tmp[p] = make_int2(ec[e] | ((r & 63) << 17), __builtin_bit_cast(int, ev[e]));
    }
}

// phase 2: one block per bucket; sequential read, write within bucket's CSR window.
__global__ __launch_bounds__(256)
void k_place(const int2* __restrict__ tmp, const int* __restrict__ rp,
             int* __restrict__ ofs, int2* __restrict__ ev2, int N) {
    const int b = blockIdx.x;
    const int row0 = b * 64;
    const int beg = rp[row0];
    const int end = rp[min(row0 + 64, N)];
    for (int e = beg + threadIdx.x; e < end; e += 256) {
        int2 t = tmp[e];
        int row = row0 + ((t.x >> 17) & 63);
        int col = t.x & 0x1FFFF;
        int pos = atomicAdd(&ofs[row], 1);
        ev2[pos] = make_int2(col, t.y);
    }
}

// ---------------- weight pack: W[K][M] fp32 -> fragment-major bf16 hi/lo ----------------
__global__ __launch_bounds__(256)
void k_packb(const float* __restrict__ W, unsigned short* __restrict__ hi,
             unsigned short* __restrict__ lo, int K, int M) {
    int idx = blockIdx.x * 256 + threadIdx.x;
    int NT = K >> 5;
    int total = (M >> 4) * NT * 64;
    if (idx >= total) return;
    int l = idx & 63;
    int t = (idx >> 6) % NT;
    int cg = idx / (NT << 6);
    int col = cg * 16 + (l & 15);
    int k0 = t * 32 + (l >> 4) * 8;
    short8 h8, l8;
    #pragma unroll
    for (int j = 0; j < 8; ++j) {
        float x = W[(size_t)(k0 + j) * M + col];
        unsigned short h = f2bf_rne(x);
        h8[j] = (short)h;
        l8[j] = (short)f2bf_rne(x - bf2f(h));
    }
    *(short8*)&hi[(size_t)idx * 8] = h8;
    *(short8*)&lo[(size_t)idx * 8] = l8;
}

// ---------------- GEMM1 (counted-vmcnt, 3-buf): C16[N,256] = fp16(X[N,512] @ W1) ----------------
__global__ __launch_bounds__(256, 3)
void k_gemm1c(const float* __restrict__ X, const unsigned short* __restrict__ Bh,
              const unsigned short* __restrict__ Bl, _Float16* __restrict__ C16, const int N) {
    constexpr int K = 512, M = 256, NT = K / 32;
    __shared__ char smem[24576];
    float* sX = (float*)smem;
    const int tid = threadIdx.x;
    const int lane = tid & 63;
    const int w = tid >> 6;
    const int lm = lane & 15, lk = lane >> 4;
    const int row0 = blockIdx.x * 64;
    const int col0 = w * 64;

    const int kseg = (lane & 7) ^ ((lane >> 3) & 7);
    const int r0 = min(row0 + w * 16 + (lane >> 3), N - 1);
    const int r1 = min(row0 + w * 16 + 8 + (lane >> 3), N - 1);
    const size_t ga0 = (size_t)r0 * K + kseg * 4;
    const size_t ga1 = (size_t)r1 * K + kseg * 4;

    const unsigned short* bfh = Bh + ((size_t)(w * 4) * NT) * 512 + lane * 8;
    const unsigned short* bfl = Bl + ((size_t)(w * 4) * NT) * 512 + lane * 8;

    f32x4 acc[4][4];
    #pragma unroll
    for (int i = 0; i < 4; ++i)
        #pragma unroll
        for (int j = 0; j < 4; ++j) acc[i][j] = (f32x4){0.f, 0.f, 0.f, 0.f};

    auto stage = [&](int bi, int kk) {
        __builtin_amdgcn_global_load_lds((const AS1 void*)(X + ga0 + kk),
                                         (AS3 void*)(sX + bi * 2048 + w * 512), 16, 0, 0);
        __builtin_amdgcn_global_load_lds((const AS1 void*)(X + ga1 + kk),
                                         (AS3 void*)(sX + bi * 2048 + w * 512 + 256), 16, 0, 0);
    };

    stage(0, 0); stage(1, 32); stage(2, 64);

    short8 bhf[4], blf[4];
    #pragma unroll
    for (int nf = 0; nf < 4; ++nf) {
        const size_t o = (size_t)nf * NT * 512;
        bhf[nf] = *(const short8*)(bfh + o);
        blf[nf] = *(const short8*)(bfl + o);
    }

    const int u0 = ((2 * lk) ^ (lm & 7)) * 4;
    const int u1 = ((2 * lk + 1) ^ (lm & 7)) * 4;
    int bi = 0;

#define G1_BODY(T, VM)                                                          \
    {                                                                           \
        vm_wait<VM>();                                                          \
        __builtin_amdgcn_s_barrier();                                           \
        __builtin_amdgcn_sched_barrier(0);                                      \
        short8 bhn[4], bln[4];                                                  \
        _Pragma("unroll")                                                       \
        for (int nf = 0; nf < 4; ++nf) { bhn[nf] = bhf[nf]; bln[nf] = blf[nf]; }\
        if ((T) + 1 < NT) {                                                     \
            _Pragma("unroll")                                                   \
            for (int nf = 0; nf < 4; ++nf) {                                    \
                const size_t o = ((size_t)nf * NT + (T) + 1) * 512;             \
                bhn[nf] = *(const short8*)(bfh + o);                            \
                bln[nf] = *(const short8*)(bfl + o);                            \
            }                                                                   \
        }                                                                       \
        __builtin_amdgcn_sched_barrier(0);                                      \
        _Pragma("unroll")                                                       \
        for (int mf = 0; mf < 4; ++mf) {                                        \
            const float* ab = sX + bi * 2048 + (mf * 16 + lm) * 32;             \
            f32x4 p0 = *(const f32x4*)(ab + u0);                                \
            f32x4 p1 = *(const f32x4*)(ab + u1);                                \
            float vv[8] = {p0.x, p0.y, p0.z, p0.w, p1.x, p1.y, p1.z, p1.w};     \
            short8 ah, al;                                                      \
            _Pragma("unroll")                                                   \
            for (int j = 0; j < 8; ++j) {                                       \
                unsigned int uu = __builtin_bit_cast(unsigned int, vv[j]);      \
                ah[j] = (short)(uu >> 16);                                      \
                float hi_ = __builtin_bit_cast(float, uu & 0xFFFF0000u);        \
                al[j] = (short)f2bf_rne(vv[j] - hi_);                           \
            }                                                                   \
            _Pragma("unroll")                                                   \
            for (int nf = 0; nf < 4; ++nf) {                                    \
                acc[mf][nf] = __builtin_amdgcn_mfma_f32_16x16x32_bf16(ah, bhf[nf], acc[mf][nf], 0, 0, 0); \
                acc[mf][nf] = __builtin_amdgcn_mfma_f32_16x16x32_bf16(ah, blf[nf], acc[mf][nf], 0, 0, 0); \
                acc[mf][nf] = __builtin_amdgcn_mfma_f32_16x16x32_bf16(al, bhf[nf], acc[mf][nf], 0, 0, 0); \
            }                                                                   \
        }                                                                       \
        lgkm0();                                                                \
        __builtin_amdgcn_sched_barrier(0);                                      \
        __builtin_amdgcn_s_barrier();                                           \
        if ((T) + 3 < NT) stage(bi, ((T) + 3) * 32);                            \
        _Pragma("unroll")                                                       \
        for (int nf = 0; nf < 4; ++nf) { bhf[nf] = bhn[nf]; blf[nf] = bln[nf]; }\
        bi = bi + 1; if (bi == 3) bi = 0;                                       \
    }

    for (int t = 0; t < NT - 2; ++t) G1_BODY(t, 12);
    G1_BODY(NT - 2, 10);
    G1_BODY(NT - 1, 8);
#undef G1_BODY

    float* sc = (float*)smem;
    #pragma unroll
    for (int mf = 0; mf < 4; ++mf) {
        __syncthreads();
        #pragma unroll
        for (int nf = 0; nf < 4; ++nf)
            #pragma unroll
            for (int r = 0; r < 4; ++r) {
                const int rl = lk * 4 + r;
                const int col = col0 + nf * 16 + lm;
                sc[rl * M + (col ^ (lk << 3))] = acc[mf][nf][r];
            }
        __syncthreads();
        #pragma unroll
        for (int i = 0; i < 4; ++i) {
            const int idx = i * 256 + tid;
            const int rl = idx >> 6, u = idx & 63;
            const int grow = row0 + mf * 16 + rl;
            if (grow < N) {
                f32x4 v = *(const f32x4*)&sc[rl * M + ((u * 4) ^ (((rl >> 2) & 3) << 3))];
                half4v h;
                h[0] = (_Float16)v[0]; h[1] = (_Float16)v[1];
                h[2] = (_Float16)v[2]; h[3] = (_Float16)v[3];
                *(half4v*)&C16[(size_t)grow * M + u * 4] = h;
            }
        }
    }
}

// ---------------- GEMM (A pre-split bf16 h/l), counted-vmcnt 3-buf, fp16 out ----------------
template <int K, int NFW>
__global__ __launch_bounds__(256, 3)
void k_gemm_btc(const unsigned short* __restrict__ Ah, const unsigned short* __restrict__ Al,
                const unsigned short* __restrict__ Bh, const unsigned short* __restrict__ Bl,
                _Float16* __restrict__ C16, const int N) {
    constexpr int M = 64 * NFW;
    constexpr int NT = K / 32;
    constexpr int UPR = 16 * NFW;
    __shared__ char smem[24576];
    unsigned short* sAh = (unsigned short*)smem;          // [3][2048]
    unsigned short* sAl = sAh + 6144;                     // [3][2048]
    const int tid = threadIdx.x;
    const int lane = tid & 63;
    const int w = tid >> 6;
    const int lm = lane & 15, lk = lane >> 4;
    const int row0 = blockIdx.x * 64;
    const int col0 = w * (16 * NFW);

    const int kseg = (lane & 3) ^ ((lane >> 2) & 3);
    const int gr = min(row0 + w * 16 + (lane >> 2), N - 1);
    const size_t ga = (size_t)gr * K + kseg * 8;

    const int aoff = lm * 32 + ((lk ^ (lm & 3)) * 8);

    const unsigned short* bfh = Bh + ((size_t)(w * NFW) * NT) * 512 + lane * 8;
    const unsigned short* bfl = Bl + ((size_t)(w * NFW) * NT) * 512 + lane * 8;

    f32x4 acc[4][NFW];
    #pragma unroll
    for (int i = 0; i < 4; ++i)
        #pragma unroll
        for (int j = 0; j < NFW; ++j) acc[i][j] = (f32x4){0.f, 0.f, 0.f, 0.f};

    auto stage = [&](int bi, int kk) {
        __builtin_amdgcn_global_load_lds((const AS1 void*)(Ah + ga + kk),
                                         (AS3 void*)(sAh + bi * 2048 + w * 512), 16, 0, 0);
        __builtin_amdgcn_global_load_lds((const AS1 void*)(Al + ga + kk),
                                         (AS3 void*)(sAl + bi * 2048 + w * 512), 16, 0, 0);
    };

    stage(0, 0); stage(1, 32); stage(2, 64);

    short8 bhf[NFW], blf[NFW];
    #pragma unroll
    for (int nf = 0; nf < NFW; ++nf) {
        const size_t o = (size_t)nf * NT * 512;
        bhf[nf] = *(const short8*)(bfh + o);
        blf[nf] = *(const short8*)(bfl + o);
    }

    int bi = 0;

#define GBT_BODY(T, VM)                                                         \
    {                                                                           \
        vm_wait<VM>();                                                          \
        __builtin_amdgcn_s_barrier();                                           \
        __builtin_amdgcn_sched_barrier(0);                                      \
        short8 bhn[NFW], bln[NFW];                                              \
        _Pragma("unroll")                                                       \
        for (int nf = 0; nf < NFW; ++nf) { bhn[nf] = bhf[nf]; bln[nf] = blf[nf]; } \
        if ((T) + 1 < NT) {                                                     \
            _Pragma("unroll")                                                   \
            for (int nf = 0; nf < NFW; ++nf) {                                  \
                const size_t o = ((size_t)nf * NT + (T) + 1) * 512;             \
                bhn[nf] = *(const short8*)(bfh + o);                            \
                bln[nf] = *(const short8*)(bfl + o);                            \
            }                                                                   \
        }                                                                       \
        __builtin_amdgcn_sched_barrier(0);                                      \
        _Pragma("unroll")                                                       \
        for (int mf = 0; mf < 4; ++mf) {                                        \
            short8 ah = *(const short8*)&sAh[bi * 2048 + aoff + mf * 512];      \
            short8 al = *(const short8*)&sAl[bi * 2048 + aoff + mf * 512];      \
            _Pragma("unroll")                                                   \
            for (int nf = 0; nf < NFW; ++nf) {                                  \
                acc[mf][nf] = __builtin_amdgcn_mfma_f32_16x16x32_bf16(ah, bhf[nf], acc[mf][nf], 0, 0, 0); \
                acc[mf][nf] = __builtin_amdgcn_mfma_f32_16x16x32_bf16(ah, blf[nf], acc[mf][nf], 0, 0, 0); \
                acc[mf][nf] = __builtin_amdgcn_mfma_f32_16x16x32_bf16(al, bhf[nf], acc[mf][nf], 0, 0, 0); \
            }                                                                   \
        }                                                                       \
        lgkm0();                                                                \
        __builtin_amdgcn_sched_barrier(0);                                      \
        __builtin_amdgcn_s_barrier();                                           \
        if ((T) + 3 < NT) stage(bi, ((T) + 3) * 32);                            \
        _Pragma("unroll")                                                       \
        for (int nf = 0; nf < NFW; ++nf) { bhf[nf] = bhn[nf]; blf[nf] = bln[nf]; } \
        bi = bi + 1; if (bi == 3) bi = 0;                                       \
    }

    for (int t = 0; t < NT - 2; ++t) GBT_BODY(t, 2 * NFW + 4);
    GBT_BODY(NT - 2, 2 * NFW + 2);
    GBT_BODY(NT - 1, 2 * NFW);
#undef GBT_BODY

    float* sc = (float*)smem;
    #pragma unroll
    for (int mf = 0; mf < 4; ++mf) {
        __syncthreads();
        #pragma unroll
        for (int nf = 0; nf < NFW; ++nf)
            #pragma unroll
            for (int r = 0; r < 4; ++r) {
                const int rl = lk * 4 + r;
                const int col = col0 + nf * 16 + lm;
                sc[rl * M + (col ^ (lk << 3))] = acc[mf][nf][r];
            }
        __syncthreads();
        #pragma unroll
        for (int i = 0; i < (16 * UPR) / 256; ++i) {
            const int idx = i * 256 + tid;
            const int rl = idx / UPR, u = idx % UPR;
            const int grow = row0 + mf * 16 + rl;
            if (grow < N) {
                f32x4 v = *(const f32x4*)&sc[rl * M + ((u * 4) ^ (((rl >> 2) & 3) << 3))];
                half4v h;
                h[0] = (_Float16)v[0]; h[1] = (_Float16)v[1];
                h[2] = (_Float16)v[2]; h[3] = (_Float16)v[3];
                *(half4v*)&C16[(size_t)grow * M + u * 4] = h;
            }
        }
    }
}

// ---------------- SpMM on fp16 input (F=256), wave-per-row, fused bias+relu+split ----------------
__global__ __launch_bounds__(256)
void k_spmm256f(const int* __restrict__ rp, const int2* __restrict__ ev2,
                const _Float16* __restrict__ in16, const float* __restrict__ bias,
                unsigned short* __restrict__ oh, unsigned short* __restrict__ ol, int N) {
    const int lane = threadIdx.x & 63;
    int r = __builtin_amdgcn_readfirstlane(blockIdx.x * 4 + (threadIdx.x >> 6));
    if (r >= N) return;
    const int e0 = __builtin_amdgcn_readfirstlane(rp[r]);
    const int e1 = __builtin_amdgcn_readfirstlane(rp[r + 1]);
    f32x4 acc = {0.f, 0.f, 0.f, 0.f};
    const _Float16* base = in16 + lane * 4;

    #pragma unroll 4
    for (int e = e0; e < e1; ++e) {
        int2 p = ev2[e];
        half4v hv = *(const half4v*)(base + (size_t)p.x * 256);
        float val = __builtin_bit_cast(float, p.y);
        acc[0] = fmaf(val, (float)hv[0], acc[0]);
        acc[1] = fmaf(val, (float)hv[1], acc[1]);
        acc[2] = fmaf(val, (float)hv[2], acc[2]);
        acc[3] = fmaf(val, (float)hv[3], acc[3]);
    }

    f32x4 bv = *(const f32x4*)&bias[lane * 4];
    ushort4v h, l;
    #pragma unroll
    for (int j = 0; j < 4; ++j) {
        float o = fmaxf(acc[j] + bv[j], 0.f);
        unsigned short hh = f2bf_rne(o);
        h[j] = hh;
        l[j] = f2bf_rne(o - bf2f(hh));
    }
    *(ushort4v*)&oh[(size_t)r * 256 + lane * 4] = h;
    *(ushort4v*)&ol[(size_t)r * 256 + lane * 4] = l;
}

// ---------------- SpMM F=128 on fp16 input + fused bias/relu + final dense ----------------
__global__ __launch_bounds__(256)
void k_spmm128f(const int* __restrict__ rp, const int2* __restrict__ ev2,
                const _Float16* __restrict__ in16, const float* __restrict__ b3,
                const float* __restrict__ Wd, const float* __restrict__ bd,
                float* __restrict__ out, int N) {
    __shared__ float Ws[H4 * NCLASS];
    __shared__ float hrow[4][H4];
    {
        int i = threadIdx.x * 8;
        *(f32x4*)&Ws[i] = *(const f32x4*)&Wd[i];
        *(f32x4*)&Ws[i + 4] = *(const f32x4*)&Wd[i + 4];
    }
    __syncthreads();

    const int lane = threadIdx.x & 63;
    const int w = threadIdx.x >> 6;
    int r = __builtin_amdgcn_readfirstlane(blockIdx.x * 4 + w);
    if (r >= N) return;
    const int e0 = __builtin_amdgcn_readfirstlane(rp[r]);
    const int e1 = __builtin_amdgcn_readfirstlane(rp[r + 1]);
    float a0 = 0.f, a1 = 0.f;
    const _Float16* base = in16 + lane * 2;

    #pragma unroll 4
    for (int e = e0; e < e1; ++e) {
        int2 p = ev2[e];
        half2v hv = *(const half2v*)(base + (size_t)p.x * 128);
        float v = __builtin_bit_cast(float, p.y);
        a0 = fmaf(v, (float)hv[0], a0);
        a1 = fmaf(v, (float)hv[1], a1);
    }

    float2 hb;
    hb.x = fmaxf(a0 + b3[lane * 2 + 0], 0.f);
    hb.y = fmaxf(a1 + b3[lane * 2 + 1], 0.f);
    *(float2*)&hrow[w][lane * 2] = hb;

    const int c = lane & 15, q = lane >> 4;
    float s = 0.f;
    #pragma unroll
    for (int k = q * 32; k < q * 32 + 32; ++k)
        s = fmaf(hrow[w][k], Ws[k * NCLASS + c], s);
    s += __shfl_xor(s, 16);
    s += __shfl_xor(s, 32);
    if (lane < 16) out[(size_t)r * NCLASS + lane] = s + bd[lane];
}

extern "C" void kernel_launch(void* const* d_in, const int* in_sizes, int n_in,
                              void* d_out, int out_size, void* d_ws, size_t ws_size,
                              hipStream_t stream) {
    const float* x  = (const float*)d_in[0];
    const int*   er = (const int*)d_in[1];
    const int*   ec = (const int*)d_in[2];
    const float* ev = (const float*)d_in[3];
    const float* W1 = (const float*)d_in[4];
    const float* b1 = (const float*)d_in[5];
    const float* W2 = (const float*)d_in[6];
    const float* b2 = (const float*)d_in[7];
    const float* W3 = (const float*)d_in[8];
    const float* b3 = (const float*)d_in[9];
    const float* Wd = (const float*)d_in[10];
    const float* bd = (const float*)d_in[11];
    float* out = (float*)d_out;

    const int N = in_sizes[0] / NFEAT;
    const int E = in_sizes[1];

    char* w = (char*)d_ws;
    auto alloc = [&](size_t bytes) { char* p = w; w += (bytes + 255) & ~(size_t)255; return p; };
    _Float16* C16 = (_Float16*)alloc((size_t)N * 256 * 2);
    unsigned short* hh = (unsigned short*)alloc((size_t)N * 256 * 2);
    unsigned short* hl = (unsigned short*)alloc((size_t)N * 256 * 2);
    int* cnt  = (int*)alloc((size_t)N * 4);
    int* rp   = (int*)alloc((size_t)(N + 1) * 4);
    int* ofs  = (int*)alloc((size_t)N * 4);
    int2* ev2 = (int2*)alloc((size_t)E * 8);
    int2* tmp = (int2*)alloc((size_t)E * 8);
    int* bsum = (int*)alloc(4096);
    int* bofs = (int*)alloc(((size_t)N / 64 + 2) * 64);
    unsigned short* W1h = (unsigned short*)alloc((size_t)NFEAT * H2 * 2);
    unsigned short* W1l = (unsigned short*)alloc((size_t)NFEAT * H2 * 2);
    unsigned short* W2h = (unsigned short*)alloc((size_t)H2 * H3 * 2);
    unsigned short* W2l = (unsigned short*)alloc((size_t)H2 * H3 * 2);
    unsigned short* W3h = (unsigned short*)alloc((size_t)H3 * H4 * 2);
    unsigned short* W3l = (unsigned short*)alloc((size_t)H3 * H4 * 2);

    const int nb = (N + 255) / 256;       // scan blocks
    const int nbk = (N + 63) / 64;        // 64-row buckets

    hipMemsetAsync(cnt, 0, (size_t)N * 4, stream);
    k_hist<<<1024, 256, 0, stream>>>(er, cnt, E);
    k_scan1<<<nb, 256, 0, stream>>>(cnt, rp, bsum, N);
    k_scan2<<<1, 512, 0, stream>>>(bsum, nb);
    k_scan3<<<nb, 256, 0, stream>>>(rp, ofs, bsum, cnt, N);
    k_binit<<<(nbk + 255) / 256, 256, 0, stream>>>(rp, bofs, nbk);
    k_bucket<<<2048, 256, 0, stream>>>(er, ec, ev, bofs, tmp, E);
    k_place<<<nbk, 256, 0, stream>>>(tmp, rp, ofs, ev2, N);

    k_packb<<<(NFEAT * H2 / 8 + 255) / 256, 256, 0, stream>>>(W1, W1h, W1l, NFEAT, H2);
    k_packb<<<(H2 * H3 / 8 + 255) / 256, 256, 0, stream>>>(W2, W2h, W2l, H2, H3);
    k_packb<<<(H3 * H4 / 8 + 255) / 256, 256, 0, stream>>>(W3, W3h, W3l, H3, H4);

    const int rgrid = (N + 63) / 64;
    const int sgrid = (N + 3) / 4;

    k_gemm1c<<<rgrid, 256, 0, stream>>>(x, W1h, W1l, C16, N);
    k_spmm256f<<<sgrid, 256, 0, stream>>>(rp, ev2, C16, b1, hh, hl, N);

    k_gemm_btc<H2, 4><<<rgrid, 256, 0, stream>>>(hh, hl, W2h, W2l, C16, N);
    k_spmm256f<<<sgrid, 256, 0, stream>>>(rp, ev2, C16, b2, hh, hl, N);

    k_gemm_btc<H3, 2><<<rgrid, 256, 0, stream>>>(hh, hl, W3h, W3l, C16, N);
    k_spmm128f<<<sgrid, 256, 0, stream>>>(rp, ev2, C16, b3, Wd, bd, out, N);
}

// Round 19
// 665.139 us; speedup vs baseline: 1.7775x; 1.1403x over previous
//
#include <hip/hip_runtime.h>
#include <hip/hip_bf16.h>
#include <cstdint>
#include <cstddef>

#define NFEAT 512
#define H2 256
#define H3 256
#define H4 128
#define NCLASS 16

typedef __attribute__((ext_vector_type(8))) short short8;
typedef __attribute__((ext_vector_type(4))) float f32x4;
typedef __attribute__((ext_vector_type(4))) unsigned short ushort4v;
typedef __attribute__((ext_vector_type(4))) _Float16 half4v;
typedef __attribute__((ext_vector_type(2))) _Float16 half2v;

#define AS1 __attribute__((address_space(1)))
#define AS3 __attribute__((address_space(3)))

__device__ inline unsigned short f2bf_rne(float x) {
    unsigned int u = __builtin_bit_cast(unsigned int, x);
    unsigned int r = (u + 0x7FFFu + ((u >> 16) & 1u)) >> 16;
    return (unsigned short)r;
}
__device__ inline float bf2f(unsigned short h) {
    return __builtin_bit_cast(float, (unsigned int)h << 16);
}

template <int VM> __device__ __forceinline__ void vm_wait() {
    asm volatile("s_waitcnt vmcnt(%0)" :: "n"(VM) : "memory");
}
__device__ __forceinline__ void lgkm0() {
    asm volatile("s_waitcnt lgkmcnt(0)" ::: "memory");
}

// ---------------- CSR build ----------------
__global__ void k_hist(const int* __restrict__ er, int* __restrict__ cnt, int E) {
    for (int e = blockIdx.x * blockDim.x + threadIdx.x; e < E; e += gridDim.x * blockDim.x)
        atomicAdd(&cnt[er[e]], 1);
}

__global__ void k_scan1(const int* __restrict__ cnt, int* __restrict__ ex,
                        int* __restrict__ bsum, int n) {
    __shared__ int s[256];
    int i = blockIdx.x * 256 + threadIdx.x;
    int v = (i < n) ? cnt[i] : 0;
    s[threadIdx.x] = v;
    __syncthreads();
    #pragma unroll
    for (int off = 1; off < 256; off <<= 1) {
        int t = (threadIdx.x >= (unsigned)off) ? s[threadIdx.x - off] : 0;
        __syncthreads();
        s[threadIdx.x] += t;
        __syncthreads();
    }
    if (i < n) ex[i] = s[threadIdx.x] - v;
    if (threadIdx.x == 255) bsum[blockIdx.x] = s[255];
}

__global__ void k_scan2(int* __restrict__ bsum, int nb) {
    __shared__ int s[512];
    int v = ((int)threadIdx.x < nb) ? bsum[threadIdx.x] : 0;
    s[threadIdx.x] = v;
    __syncthreads();
    #pragma unroll
    for (int off = 1; off < 512; off <<= 1) {
        int t = (threadIdx.x >= (unsigned)off) ? s[threadIdx.x - off] : 0;
        __syncthreads();
        s[threadIdx.x] += t;
        __syncthreads();
    }
    if ((int)threadIdx.x < nb) bsum[threadIdx.x] = s[threadIdx.x] - v;
}

__global__ void k_scan3(int* __restrict__ rp, int* __restrict__ ofs,
                        const int* __restrict__ bsum, const int* __restrict__ cnt,
                        int n) {
    int i = blockIdx.x * 256 + threadIdx.x;
    if (i < n) {
        int v = rp[i] + bsum[blockIdx.x];
        rp[i] = v;
        ofs[i] = v;
        if (i == n - 1) rp[n] = v + cnt[i];
    }
}

// sliced scatter: slice s commits only rows in its N/8 window -> destination
// region (~1.6MB) is L2-resident on its XCD -> full-line writeback, cheap atomics.
__global__ void k_scatter_sl(const int* __restrict__ er, const int* __restrict__ ec,
                             const float* __restrict__ ev, int* __restrict__ ofs,
                             int2* __restrict__ ev2, int E, int sliceSz) {
    const int slice = blockIdx.x & 7;
    const int g = blockIdx.x >> 3;           // 0..255 groups per slice
    const int rlo = slice * sliceSz;
    const int rhi = rlo + sliceSz;
    for (int e = g * 256 + threadIdx.x; e < E; e += 256 * 256) {
        int r = er[e];
        if (r >= rlo && r < rhi) {
            int p = atomicAdd(&ofs[r], 1);
            ev2[p] = make_int2(ec[e], __builtin_bit_cast(int, ev[e]));
        }
    }
}

// ---------------- weight pack: W[K][M] fp32 -> fragment-major bf16 hi/lo ----------------
__global__ __launch_bounds__(256)
void k_packb(const float* __restrict__ W, unsigned short* __restrict__ hi,
             unsigned short* __restrict__ lo, int K, int M) {
    int idx = blockIdx.x * 256 + threadIdx.x;
    int NT = K >> 5;
    int total = (M >> 4) * NT * 64;
    if (idx >= total) return;
    int l = idx & 63;
    int t = (idx >> 6) % NT;
    int cg = idx / (NT << 6);
    int col = cg * 16 + (l & 15);
    int k0 = t * 32 + (l >> 4) * 8;
    short8 h8, l8;
    #pragma unroll
    for (int j = 0; j < 8; ++j) {
        float x = W[(size_t)(k0 + j) * M + col];
        unsigned short h = f2bf_rne(x);
        h8[j] = (short)h;
        l8[j] = (short)f2bf_rne(x - bf2f(h));
    }
    *(short8*)&hi[(size_t)idx * 8] = h8;
    *(short8*)&lo[(size_t)idx * 8] = l8;
}

// ---------------- GEMM1 (counted-vmcnt, 3-buf): C16[N,256] = fp16(X[N,512] @ W1) ----------------
__global__ __launch_bounds__(256, 3)
void k_gemm1c(const float* __restrict__ X, const unsigned short* __restrict__ Bh,
              const unsigned short* __restrict__ Bl, _Float16* __restrict__ C16, const int N) {
    constexpr int K = 512, M = 256, NT = K / 32;
    __shared__ char smem[24576];
    float* sX = (float*)smem;
    const int tid = threadIdx.x;
    const int lane = tid & 63;
    const int w = tid >> 6;
    const int lm = lane & 15, lk = lane >> 4;
    const int row0 = blockIdx.x * 64;
    const int col0 = w * 64;

    const int kseg = (lane & 7) ^ ((lane >> 3) & 7);
    const int r0 = min(row0 + w * 16 + (lane >> 3), N - 1);
    const int r1 = min(row0 + w * 16 + 8 + (lane >> 3), N - 1);
    const size_t ga0 = (size_t)r0 * K + kseg * 4;
    const size_t ga1 = (size_t)r1 * K + kseg * 4;

    const unsigned short* bfh = Bh + ((size_t)(w * 4) * NT) * 512 + lane * 8;
    const unsigned short* bfl = Bl + ((size_t)(w * 4) * NT) * 512 + lane * 8;

    f32x4 acc[4][4];
    #pragma unroll
    for (int i = 0; i < 4; ++i)
        #pragma unroll
        for (int j = 0; j < 4; ++j) acc[i][j] = (f32x4){0.f, 0.f, 0.f, 0.f};

    auto stage = [&](int bi, int kk) {
        __builtin_amdgcn_global_load_lds((const AS1 void*)(X + ga0 + kk),
                                         (AS3 void*)(sX + bi * 2048 + w * 512), 16, 0, 0);
        __builtin_amdgcn_global_load_lds((const AS1 void*)(X + ga1 + kk),
                                         (AS3 void*)(sX + bi * 2048 + w * 512 + 256), 16, 0, 0);
    };

    stage(0, 0); stage(1, 32); stage(2, 64);

    short8 bhf[4], blf[4];
    #pragma unroll
    for (int nf = 0; nf < 4; ++nf) {
        const size_t o = (size_t)nf * NT * 512;
        bhf[nf] = *(const short8*)(bfh + o);
        blf[nf] = *(const short8*)(bfl + o);
    }

    const int u0 = ((2 * lk) ^ (lm & 7)) * 4;
    const int u1 = ((2 * lk + 1) ^ (lm & 7)) * 4;
    int bi = 0;

#define G1_BODY(T, VM)                                                          \
    {                                                                           \
        vm_wait<VM>();                                                          \
        __builtin_amdgcn_s_barrier();                                           \
        __builtin_amdgcn_sched_barrier(0);                                      \
        short8 bhn[4], bln[4];                                                  \
        _Pragma("unroll")                                                       \
        for (int nf = 0; nf < 4; ++nf) { bhn[nf] = bhf[nf]; bln[nf] = blf[nf]; }\
        if ((T) + 1 < NT) {                                                     \
            _Pragma("unroll")                                                   \
            for (int nf = 0; nf < 4; ++nf) {                                    \
                const size_t o = ((size_t)nf * NT + (T) + 1) * 512;             \
                bhn[nf] = *(const short8*)(bfh + o);                            \
                bln[nf] = *(const short8*)(bfl + o);                            \
            }                                                                   \
        }                                                                       \
        __builtin_amdgcn_sched_barrier(0);                                      \
        _Pragma("unroll")                                                       \
        for (int mf = 0; mf < 4; ++mf) {                                        \
            const float* ab = sX + bi * 2048 + (mf * 16 + lm) * 32;             \
            f32x4 p0 = *(const f32x4*)(ab + u0);                                \
            f32x4 p1 = *(const f32x4*)(ab + u1);                                \
            float vv[8] = {p0.x, p0.y, p0.z, p0.w, p1.x, p1.y, p1.z, p1.w};     \
            short8 ah, al;                                                      \
            _Pragma("unroll")                                                   \
            for (int j = 0; j < 8; ++j) {                                       \
                unsigned int uu = __builtin_bit_cast(unsigned int, vv[j]);      \
                ah[j] = (short)(uu >> 16);                                      \
                float hi_ = __builtin_bit_cast(float, uu & 0xFFFF0000u);        \
                al[j] = (short)f2bf_rne(vv[j] - hi_);                           \
            }                                                                   \
            _Pragma("unroll")                                                   \
            for (int nf = 0; nf < 4; ++nf) {                                    \
                acc[mf][nf] = __builtin_amdgcn_mfma_f32_16x16x32_bf16(ah, bhf[nf], acc[mf][nf], 0, 0, 0); \
                acc[mf][nf] = __builtin_amdgcn_mfma_f32_16x16x32_bf16(ah, blf[nf], acc[mf][nf], 0, 0, 0); \
                acc[mf][nf] = __builtin_amdgcn_mfma_f32_16x16x32_bf16(al, bhf[nf], acc[mf][nf], 0, 0, 0); \
            }                                                                   \
        }                                                                       \
        lgkm0();                                                                \
        __builtin_amdgcn_sched_barrier(0);                                      \
        __builtin_amdgcn_s_barrier();                                           \
        if ((T) + 3 < NT) stage(bi, ((T) + 3) * 32);                            \
        _Pragma("unroll")                                                       \
        for (int nf = 0; nf < 4; ++nf) { bhf[nf] = bhn[nf]; blf[nf] = bln[nf]; }\
        bi = bi + 1; if (bi == 3) bi = 0;                                       \
    }

    for (int t = 0; t < NT - 2; ++t) G1_BODY(t, 12);
    G1_BODY(NT - 2, 10);
    G1_BODY(NT - 1, 8);
#undef G1_BODY

    float* sc = (float*)smem;
    #pragma unroll
    for (int mf = 0; mf < 4; ++mf) {
        __syncthreads();
        #pragma unroll
        for (int nf = 0; nf < 4; ++nf)
            #pragma unroll
            for (int r = 0; r < 4; ++r) {
                const int rl = lk * 4 + r;
                const int col = col0 + nf * 16 + lm;
                sc[rl * M + (col ^ (lk << 3))] = acc[mf][nf][r];
            }
        __syncthreads();
        #pragma unroll
        for (int i = 0; i < 4; ++i) {
            const int idx = i * 256 + tid;
            const int rl = idx >> 6, u = idx & 63;
            const int grow = row0 + mf * 16 + rl;
            if (grow < N) {
                f32x4 v = *(const f32x4*)&sc[rl * M + ((u * 4) ^ (((rl >> 2) & 3) << 3))];
                half4v h;
                h[0] = (_Float16)v[0]; h[1] = (_Float16)v[1];
                h[2] = (_Float16)v[2]; h[3] = (_Float16)v[3];
                *(half4v*)&C16[(size_t)grow * M + u * 4] = h;
            }
        }
    }
}

// ---------------- GEMM (A pre-split bf16 h/l), counted-vmcnt 3-buf, fp16 out ----------------
template <int K, int NFW>
__global__ __launch_bounds__(256, 3)
void k_gemm_btc(const unsigned short* __restrict__ Ah, const unsigned short* __restrict__ Al,
                const unsigned short* __restrict__ Bh, const unsigned short* __restrict__ Bl,
                _Float16* __restrict__ C16, const int N) {
    constexpr int M = 64 * NFW;
    constexpr int NT = K / 32;
    constexpr int UPR = 16 * NFW;
    __shared__ char smem[24576];
    unsigned short* sAh = (unsigned short*)smem;          // [3][2048]
    unsigned short* sAl = sAh + 6144;                     // [3][2048]
    const int tid = threadIdx.x;
    const int lane = tid & 63;
    const int w = tid >> 6;
    const int lm = lane & 15, lk = lane >> 4;
    const int row0 = blockIdx.x * 64;
    const int col0 = w * (16 * NFW);

    const int kseg = (lane & 3) ^ ((lane >> 2) & 3);
    const int gr = min(row0 + w * 16 + (lane >> 2), N - 1);
    const size_t ga = (size_t)gr * K + kseg * 8;

    const int aoff = lm * 32 + ((lk ^ (lm & 3)) * 8);

    const unsigned short* bfh = Bh + ((size_t)(w * NFW) * NT) * 512 + lane * 8;
    const unsigned short* bfl = Bl + ((size_t)(w * NFW) * NT) * 512 + lane * 8;

    f32x4 acc[4][NFW];
    #pragma unroll
    for (int i = 0; i < 4; ++i)
        #pragma unroll
        for (int j = 0; j < NFW; ++j) acc[i][j] = (f32x4){0.f, 0.f, 0.f, 0.f};

    auto stage = [&](int bi, int kk) {
        __builtin_amdgcn_global_load_lds((const AS1 void*)(Ah + ga + kk),
                                         (AS3 void*)(sAh + bi * 2048 + w * 512), 16, 0, 0);
        __builtin_amdgcn_global_load_lds((const AS1 void*)(Al + ga + kk),
                                         (AS3 void*)(sAl + bi * 2048 + w * 512), 16, 0, 0);
    };

    stage(0, 0); stage(1, 32); stage(2, 64);

    short8 bhf[NFW], blf[NFW];
    #pragma unroll
    for (int nf = 0; nf < NFW; ++nf) {
        const size_t o = (size_t)nf * NT * 512;
        bhf[nf] = *(const short8*)(bfh + o);
        blf[nf] = *(const short8*)(bfl + o);
    }

    int bi = 0;

#define GBT_BODY(T, VM)                                                         \
    {                                                                           \
        vm_wait<VM>();                                                          \
        __builtin_amdgcn_s_barrier();                                           \
        __builtin_amdgcn_sched_barrier(0);                                      \
        short8 bhn[NFW], bln[NFW];                                              \
        _Pragma("unroll")                                                       \
        for (int nf = 0; nf < NFW; ++nf) { bhn[nf] = bhf[nf]; bln[nf] = blf[nf]; } \
        if ((T) + 1 < NT) {                                                     \
            _Pragma("unroll")                                                   \
            for (int nf = 0; nf < NFW; ++nf) {                                  \
                const size_t o = ((size_t)nf * NT + (T) + 1) * 512;             \
                bhn[nf] = *(const short8*)(bfh + o);                            \
                bln[nf] = *(const short8*)(bfl + o);                            \
            }                                                                   \
        }                                                                       \
        __builtin_amdgcn_sched_barrier(0);                                      \
        _Pragma("unroll")                                                       \
        for (int mf = 0; mf < 4; ++mf) {                                        \
            short8 ah = *(const short8*)&sAh[bi * 2048 + aoff + mf * 512];      \
            short8 al = *(const short8*)&sAl[bi * 2048 + aoff + mf * 512];      \
            _Pragma("unroll")                                                   \
            for (int nf = 0; nf < NFW; ++nf) {                                  \
                acc[mf][nf] = __builtin_amdgcn_mfma_f32_16x16x32_bf16(ah, bhf[nf], acc[mf][nf], 0, 0, 0); \
                acc[mf][nf] = __builtin_amdgcn_mfma_f32_16x16x32_bf16(ah, blf[nf], acc[mf][nf], 0, 0, 0); \
                acc[mf][nf] = __builtin_amdgcn_mfma_f32_16x16x32_bf16(al, bhf[nf], acc[mf][nf], 0, 0, 0); \
            }                                                                   \
        }                                                                       \
        lgkm0();                                                                \
        __builtin_amdgcn_sched_barrier(0);                                      \
        __builtin_amdgcn_s_barrier();                                           \
        if ((T) + 3 < NT) stage(bi, ((T) + 3) * 32);                            \
        _Pragma("unroll")                                                       \
        for (int nf = 0; nf < NFW; ++nf) { bhf[nf] = bhn[nf]; blf[nf] = bln[nf]; } \
        bi = bi + 1; if (bi == 3) bi = 0;                                       \
    }

    for (int t = 0; t < NT - 2; ++t) GBT_BODY(t, 2 * NFW + 4);
    GBT_BODY(NT - 2, 2 * NFW + 2);
    GBT_BODY(NT - 1, 2 * NFW);
#undef GBT_BODY

    float* sc = (float*)smem;
    #pragma unroll
    for (int mf = 0; mf < 4; ++mf) {
        __syncthreads();
        #pragma unroll
        for (int nf = 0; nf < NFW; ++nf)
            #pragma unroll
            for (int r = 0; r < 4; ++r) {
                const int rl = lk * 4 + r;
                const int col = col0 + nf * 16 + lm;
                sc[rl * M + (col ^ (lk << 3))] = acc[mf][nf][r];
            }
        __syncthreads();
        #pragma unroll
        for (int i = 0; i < (16 * UPR) / 256; ++i) {
            const int idx = i * 256 + tid;
            const int rl = idx / UPR, u = idx % UPR;
            const int grow = row0 + mf * 16 + rl;
            if (grow < N) {
                f32x4 v = *(const f32x4*)&sc[rl * M + ((u * 4) ^ (((rl >> 2) & 3) << 3))];
                half4v h;
                h[0] = (_Float16)v[0]; h[1] = (_Float16)v[1];
                h[2] = (_Float16)v[2]; h[3] = (_Float16)v[3];
                *(half4v*)&C16[(size_t)grow * M + u * 4] = h;
            }
        }
    }
}

// ---------------- SpMM on fp16 input (F=256), wave-per-row, fused bias+relu+split ----------------
__global__ __launch_bounds__(256)
void k_spmm256f(const int* __restrict__ rp, const int2* __restrict__ ev2,
                const _Float16* __restrict__ in16, const float* __restrict__ bias,
                unsigned short* __restrict__ oh, unsigned short* __restrict__ ol, int N) {
    const int lane = threadIdx.x & 63;
    int r = __builtin_amdgcn_readfirstlane(blockIdx.x * 4 + (threadIdx.x >> 6));
    if (r >= N) return;
    const int e0 = __builtin_amdgcn_readfirstlane(rp[r]);
    const int e1 = __builtin_amdgcn_readfirstlane(rp[r + 1]);
    f32x4 acc = {0.f, 0.f, 0.f, 0.f};
    const _Float16* base = in16 + lane * 4;

    #pragma unroll 4
    for (int e = e0; e < e1; ++e) {
        int2 p = ev2[e];
        half4v hv = *(const half4v*)(base + (size_t)p.x * 256);
        float val = __builtin_bit_cast(float, p.y);
        acc[0] = fmaf(val, (float)hv[0], acc[0]);
        acc[1] = fmaf(val, (float)hv[1], acc[1]);
        acc[2] = fmaf(val, (float)hv[2], acc[2]);
        acc[3] = fmaf(val, (float)hv[3], acc[3]);
    }

    f32x4 bv = *(const f32x4*)&bias[lane * 4];
    ushort4v h, l;
    #pragma unroll
    for (int j = 0; j < 4; ++j) {
        float o = fmaxf(acc[j] + bv[j], 0.f);
        unsigned short hh = f2bf_rne(o);
        h[j] = hh;
        l[j] = f2bf_rne(o - bf2f(hh));
    }
    *(ushort4v*)&oh[(size_t)r * 256 + lane * 4] = h;
    *(ushort4v*)&ol[(size_t)r * 256 + lane * 4] = l;
}

// ---------------- SpMM F=128 on fp16 input + fused bias/relu + final dense ----------------
__global__ __launch_bounds__(256)
void k_spmm128f(const int* __restrict__ rp, const int2* __restrict__ ev2,
                const _Float16* __restrict__ in16, const float* __restrict__ b3,
                const float* __restrict__ Wd, const float* __restrict__ bd,
                float* __restrict__ out, int N) {
    __shared__ float Ws[H4 * NCLASS];
    __shared__ float hrow[4][H4];
    {
        int i = threadIdx.x * 8;
        *(f32x4*)&Ws[i] = *(const f32x4*)&Wd[i];
        *(f32x4*)&Ws[i + 4] = *(const f32x4*)&Wd[i + 4];
    }
    __syncthreads();

    const int lane = threadIdx.x & 63;
    const int w = threadIdx.x >> 6;
    int r = __builtin_amdgcn_readfirstlane(blockIdx.x * 4 + w);
    if (r >= N) return;
    const int e0 = __builtin_amdgcn_readfirstlane(rp[r]);
    const int e1 = __builtin_amdgcn_readfirstlane(rp[r + 1]);
    float a0 = 0.f, a1 = 0.f;
    const _Float16* base = in16 + lane * 2;

    #pragma unroll 4
    for (int e = e0; e < e1; ++e) {
        int2 p = ev2[e];
        half2v hv = *(const half2v*)(base + (size_t)p.x * 128);
        float v = __builtin_bit_cast(float, p.y);
        a0 = fmaf(v, (float)hv[0], a0);
        a1 = fmaf(v, (float)hv[1], a1);
    }

    float2 hb;
    hb.x = fmaxf(a0 + b3[lane * 2 + 0], 0.f);
    hb.y = fmaxf(a1 + b3[lane * 2 + 1], 0.f);
    *(float2*)&hrow[w][lane * 2] = hb;

    const int c = lane & 15, q = lane >> 4;
    float s = 0.f;
    #pragma unroll
    for (int k = q * 32; k < q * 32 + 32; ++k)
        s = fmaf(hrow[w][k], Ws[k * NCLASS + c], s);
    s += __shfl_xor(s, 16);
    s += __shfl_xor(s, 32);
    if (lane < 16) out[(size_t)r * NCLASS + lane] = s + bd[lane];
}

extern "C" void kernel_launch(void* const* d_in, const int* in_sizes, int n_in,
                              void* d_out, int out_size, void* d_ws, size_t ws_size,
                              hipStream_t stream) {
    const float* x  = (const float*)d_in[0];
    const int*   er = (const int*)d_in[1];
    const int*   ec = (const int*)d_in[2];
    const float* ev = (const float*)d_in[3];
    const float* W1 = (const float*)d_in[4];
    const float* b1 = (const float*)d_in[5];
    const float* W2 = (const float*)d_in[6];
    const float* b2 = (const float*)d_in[7];
    const float* W3 = (const float*)d_in[8];
    const float* b3 = (const float*)d_in[9];
    const float* Wd = (const float*)d_in[10];
    const float* bd = (const float*)d_in[11];
    float* out = (float*)d_out;

    const int N = in_sizes[0] / NFEAT;
    const int E = in_sizes[1];

    char* w = (char*)d_ws;
    auto alloc = [&](size_t bytes) { char* p = w; w += (bytes + 255) & ~(size_t)255; return p; };
    _Float16* C16 = (_Float16*)alloc((size_t)N * 256 * 2);
    unsigned short* hh = (unsigned short*)alloc((size_t)N * 256 * 2);
    unsigned short* hl = (unsigned short*)alloc((size_t)N * 256 * 2);
    int* cnt  = (int*)alloc((size_t)N * 4);
    int* rp   = (int*)alloc((size_t)(N + 1) * 4);
    int* ofs  = (int*)alloc((size_t)N * 4);
    int2* ev2 = (int2*)alloc((size_t)E * 8);
    int* bsum = (int*)alloc(4096);
    unsigned short* W1h = (unsigned short*)alloc((size_t)NFEAT * H2 * 2);
    unsigned short* W1l = (unsigned short*)alloc((size_t)NFEAT * H2 * 2);
    unsigned short* W2h = (unsigned short*)alloc((size_t)H2 * H3 * 2);
    unsigned short* W2l = (unsigned short*)alloc((size_t)H2 * H3 * 2);
    unsigned short* W3h = (unsigned short*)alloc((size_t)H3 * H4 * 2);
    unsigned short* W3l = (unsigned short*)alloc((size_t)H3 * H4 * 2);

    const int nb = (N + 255) / 256;
    const int sliceSz = (N + 7) / 8;

    hipMemsetAsync(cnt, 0, (size_t)N * 4, stream);
    k_hist<<<1024, 256, 0, stream>>>(er, cnt, E);
    k_scan1<<<nb, 256, 0, stream>>>(cnt, rp, bsum, N);
    k_scan2<<<1, 512, 0, stream>>>(bsum, nb);
    k_scan3<<<nb, 256, 0, stream>>>(rp, ofs, bsum, cnt, N);
    k_scatter_sl<<<2048, 256, 0, stream>>>(er, ec, ev, ofs, ev2, E, sliceSz);

    k_packb<<<(NFEAT * H2 / 8 + 255) / 256, 256, 0, stream>>>(W1, W1h, W1l, NFEAT, H2);
    k_packb<<<(H2 * H3 / 8 + 255) / 256, 256, 0, stream>>>(W2, W2h, W2l, H2, H3);
    k_packb<<<(H3 * H4 / 8 + 255) / 256, 256, 0, stream>>>(W3, W3h, W3l, H3, H4);

    const int rgrid = (N + 63) / 64;
    const int sgrid = (N + 3) / 4;

    k_gemm1c<<<rgrid, 256, 0, stream>>>(x, W1h, W1l, C16, N);
    k_spmm256f<<<sgrid, 256, 0, stream>>>(rp, ev2, C16, b1, hh, hl, N);

    k_gemm_btc<H2, 4><<<rgrid, 256, 0, stream>>>(hh, hl, W2h, W2l, C16, N);
    k_spmm256f<<<sgrid, 256, 0, stream>>>(rp, ev2, C16, b2, hh, hl, N);

    k_gemm_btc<H3, 2><<<rgrid, 256, 0, stream>>>(hh, hl, W3h, W3l, C16, N);
    k_spmm128f<<<sgrid, 256, 0, stream>>>(rp, ev2, C16, b3, Wd, bd, out, N);
}

// Round 20
// 656.071 us; speedup vs baseline: 1.8021x; 1.0138x over previous
//
#include <hip/hip_runtime.h>
#include <hip/hip_bf16.h>
#include <cstdint>
#include <cstddef>

#define NFEAT 512
#define H2 256
#define H3 256
#define H4 128
#define NCLASS 16

typedef __attribute__((ext_vector_type(8))) short short8;
typedef __attribute__((ext_vector_type(4))) float f32x4;
typedef __attribute__((ext_vector_type(4))) unsigned short ushort4v;
typedef __attribute__((ext_vector_type(4))) _Float16 half4v;
typedef __attribute__((ext_vector_type(2))) _Float16 half2v;

#define AS1 __attribute__((address_space(1)))
#define AS3 __attribute__((address_space(3)))

__device__ inline unsigned short f2bf_rne(float x) {
    unsigned int u = __builtin_bit_cast(unsigned int, x);
    unsigned int r = (u + 0x7FFFu + ((u >> 16) & 1u)) >> 16;
    return (unsigned short)r;
}
__device__ inline float bf2f(unsigned short h) {
    return __builtin_bit_cast(float, (unsigned int)h << 16);
}

template <int VM> __device__ __forceinline__ void vm_wait() {
    asm volatile("s_waitcnt vmcnt(%0)" :: "n"(VM) : "memory");
}
__device__ __forceinline__ void lgkm0() {
    asm volatile("s_waitcnt lgkmcnt(0)" ::: "memory");
}

// ---------------- CSR build ----------------
__global__ void k_hist(const int* __restrict__ er, int* __restrict__ cnt, int E) {
    for (int e = blockIdx.x * blockDim.x + threadIdx.x; e < E; e += gridDim.x * blockDim.x)
        atomicAdd(&cnt[er[e]], 1);
}

__global__ void k_scan1(const int* __restrict__ cnt, int* __restrict__ ex,
                        int* __restrict__ bsum, int n) {
    __shared__ int s[256];
    int i = blockIdx.x * 256 + threadIdx.x;
    int v = (i < n) ? cnt[i] : 0;
    s[threadIdx.x] = v;
    __syncthreads();
    #pragma unroll
    for (int off = 1; off < 256; off <<= 1) {
        int t = (threadIdx.x >= (unsigned)off) ? s[threadIdx.x - off] : 0;
        __syncthreads();
        s[threadIdx.x] += t;
        __syncthreads();
    }
    if (i < n) ex[i] = s[threadIdx.x] - v;
    if (threadIdx.x == 255) bsum[blockIdx.x] = s[255];
}

__global__ void k_scan2(int* __restrict__ bsum, int nb) {
    __shared__ int s[512];
    int v = ((int)threadIdx.x < nb) ? bsum[threadIdx.x] : 0;
    s[threadIdx.x] = v;
    __syncthreads();
    #pragma unroll
    for (int off = 1; off < 512; off <<= 1) {
        int t = (threadIdx.x >= (unsigned)off) ? s[threadIdx.x - off] : 0;
        __syncthreads();
        s[threadIdx.x] += t;
        __syncthreads();
    }
    if ((int)threadIdx.x < nb) bsum[threadIdx.x] = s[threadIdx.x] - v;
}

__global__ void k_scan3(int* __restrict__ rp, int* __restrict__ ofs,
                        const int* __restrict__ bsum, const int* __restrict__ cnt,
                        int n) {
    int i = blockIdx.x * 256 + threadIdx.x;
    if (i < n) {
        int v = rp[i] + bsum[blockIdx.x];
        rp[i] = v;
        ofs[i] = v;
        if (i == n - 1) rp[n] = v + cnt[i];
    }
}

// sliced scatter: slice s commits only rows in its N/8 window -> destination
// region (~1.6MB) is L2-resident on its XCD -> full-line writeback, cheap atomics.
__global__ void k_scatter_sl(const int* __restrict__ er, const int* __restrict__ ec,
                             const float* __restrict__ ev, int* __restrict__ ofs,
                             int2* __restrict__ ev2, int E, int sliceSz) {
    const int slice = blockIdx.x & 7;
    const int g = blockIdx.x >> 3;
    const int rlo = slice * sliceSz;
    const int rhi = rlo + sliceSz;
    for (int e = g * 256 + threadIdx.x; e < E; e += 256 * 256) {
        int r = er[e];
        if (r >= rlo && r < rhi) {
            int p = atomicAdd(&ofs[r], 1);
            ev2[p] = make_int2(ec[e], __builtin_bit_cast(int, ev[e]));
        }
    }
}

// ---------------- weight pack: W[K][M] fp32 -> fragment-major bf16 hi/lo ----------------
__global__ __launch_bounds__(256)
void k_packb(const float* __restrict__ W, unsigned short* __restrict__ hi,
             unsigned short* __restrict__ lo, int K, int M) {
    int idx = blockIdx.x * 256 + threadIdx.x;
    int NT = K >> 5;
    int total = (M >> 4) * NT * 64;
    if (idx >= total) return;
    int l = idx & 63;
    int t = (idx >> 6) % NT;
    int cg = idx / (NT << 6);
    int col = cg * 16 + (l & 15);
    int k0 = t * 32 + (l >> 4) * 8;
    short8 h8, l8;
    #pragma unroll
    for (int j = 0; j < 8; ++j) {
        float x = W[(size_t)(k0 + j) * M + col];
        unsigned short h = f2bf_rne(x);
        h8[j] = (short)h;
        l8[j] = (short)f2bf_rne(x - bf2f(h));
    }
    *(short8*)&hi[(size_t)idx * 8] = h8;
    *(short8*)&lo[(size_t)idx * 8] = l8;
}

// ---------------- GEMM1 (counted-vmcnt, 3 fp32 bufs, cooperative convert to
// 2 bf16 dbuf): C16[N,256] = fp16(X[N,512] @ W1). Each element converted ONCE.
__global__ __launch_bounds__(256, 3)
void k_gemm1d(const float* __restrict__ X, const unsigned short* __restrict__ Bh,
              const unsigned short* __restrict__ Bl, _Float16* __restrict__ C16, const int N) {
    constexpr int K = 512, M = 256, NT = K / 32;
    __shared__ char smem[40960];
    float* sXf = (float*)smem;                               // 3 x 2048 fp32 (24 KB)
    unsigned short* sAh = (unsigned short*)(smem + 24576);   // 2 x 2048 bf16 (8 KB)
    unsigned short* sAl = (unsigned short*)(smem + 32768);   // 2 x 2048 bf16 (8 KB)
    const int tid = threadIdx.x;
    const int lane = tid & 63;
    const int w = tid >> 6;
    const int lm = lane & 15, lk = lane >> 4;
    const int row0 = blockIdx.x * 64;
    const int col0 = w * 64;

    // fp32 staging: wave w stages its own rows [w*16, w*16+16)
    const int kseg = (lane & 7) ^ ((lane >> 3) & 7);
    const int r0 = min(row0 + w * 16 + (lane >> 3), N - 1);
    const int r1 = min(row0 + w * 16 + 8 + (lane >> 3), N - 1);
    const size_t ga0 = (size_t)r0 * K + kseg * 4;
    const size_t ga1 = (size_t)r1 * K + kseg * 4;

    // cooperative convert: wave w converts its OWN 16 rows (r10-verified mapping)
    const int crow = w * 16 + (lane >> 2);
    const int ch = lane & 3;
    const int cu0 = ((2 * ch) ^ (crow & 7)) * 4;
    const int cu1 = ((2 * ch + 1) ^ (crow & 7)) * 4;
    const int cwo = crow * 32 + (ch ^ (crow & 3)) * 8;

    // fragment-major B: wave w owns col groups [w*4, w*4+4)
    const unsigned short* bfh = Bh + ((size_t)(w * 4) * NT) * 512 + lane * 8;
    const unsigned short* bfl = Bl + ((size_t)(w * 4) * NT) * 512 + lane * 8;
    const int aoff = lm * 32 + ((lk ^ (lm & 3)) * 8);

    f32x4 acc[4][4];
    #pragma unroll
    for (int i = 0; i < 4; ++i)
        #pragma unroll
        for (int j = 0; j < 4; ++j) acc[i][j] = (f32x4){0.f, 0.f, 0.f, 0.f};

    auto stage = [&](int bi, int kk) {
        __builtin_amdgcn_global_load_lds((const AS1 void*)(X + ga0 + kk),
                                         (AS3 void*)(sXf + bi * 2048 + w * 512), 16, 0, 0);
        __builtin_amdgcn_global_load_lds((const AS1 void*)(X + ga1 + kk),
                                         (AS3 void*)(sXf + bi * 2048 + w * 512 + 256), 16, 0, 0);
    };

    auto convert = [&](int src, int dst) {
        const float* s = sXf + src * 2048 + crow * 32;
        f32x4 p0 = *(const f32x4*)(s + cu0);
        f32x4 p1 = *(const f32x4*)(s + cu1);
        float vv[8] = {p0.x, p0.y, p0.z, p0.w, p1.x, p1.y, p1.z, p1.w};
        short8 ah, al;
        #pragma unroll
        for (int j = 0; j < 8; ++j) {
            unsigned int uu = __builtin_bit_cast(unsigned int, vv[j]);
            ah[j] = (short)(uu >> 16);
            float hi_ = __builtin_bit_cast(float, uu & 0xFFFF0000u);
            al[j] = (short)f2bf_rne(vv[j] - hi_);
        }
        *(short8*)&sAh[dst * 2048 + cwo] = ah;
        *(short8*)&sAl[dst * 2048 + cwo] = al;
    };

    // prologue: 3 stages in flight, B(0) frags, convert(0)
    stage(0, 0); stage(1, 32); stage(2, 64);
    short8 bhf[4], blf[4];
    #pragma unroll
    for (int nf = 0; nf < 4; ++nf) {
        const size_t o = (size_t)nf * NT * 512;
        bhf[nf] = *(const short8*)(bfh + o);
        blf[nf] = *(const short8*)(bfl + o);
    }
    vm_wait<12>();                     // stage(0) done (B0[8]+stage1[2]+stage2[2] left)
    convert(0, 0);
    lgkm0();
    __builtin_amdgcn_s_barrier();      // bf16[0] published

    int b0 = 0;                        // = t % 3 (stage target); convert src = b0+1 mod 3

#define G1D_BODY(T, VM)                                                         \
    {                                                                           \
        vm_wait<VM>();                                                          \
        __builtin_amdgcn_s_barrier();                                           \
        __builtin_amdgcn_sched_barrier(0);                                      \
        short8 bhn[4], bln[4];                                                  \
        _Pragma("unroll")                                                       \
        for (int nf = 0; nf < 4; ++nf) { bhn[nf] = bhf[nf]; bln[nf] = blf[nf]; }\
        if ((T) + 1 < NT) {                                                     \
            _Pragma("unroll")                                                   \
            for (int nf = 0; nf < 4; ++nf) {                                    \
                const size_t o = ((size_t)nf * NT + (T) + 1) * 512;             \
                bhn[nf] = *(const short8*)(bfh + o);                            \
                bln[nf] = *(const short8*)(bfl + o);                            \
            }                                                                   \
        }                                                                       \
        __builtin_amdgcn_sched_barrier(0);                                      \
        _Pragma("unroll")                                                       \
        for (int mf = 0; mf < 4; ++mf) {                                        \
            short8 ah = *(const short8*)&sAh[((T) & 1) * 2048 + aoff + mf * 512]; \
            short8 al = *(const short8*)&sAl[((T) & 1) * 2048 + aoff + mf * 512]; \
            _Pragma("unroll")                                                   \
            for (int nf = 0; nf < 4; ++nf) {                                    \
                acc[mf][nf] = __builtin_amdgcn_mfma_f32_16x16x32_bf16(ah, bhf[nf], acc[mf][nf], 0, 0, 0); \
                acc[mf][nf] = __builtin_amdgcn_mfma_f32_16x16x32_bf16(ah, blf[nf], acc[mf][nf], 0, 0, 0); \
                acc[mf][nf] = __builtin_amdgcn_mfma_f32_16x16x32_bf16(al, bhf[nf], acc[mf][nf], 0, 0, 0); \
            }                                                                   \
        }                                                                       \
        if ((T) + 1 < NT) {                                                     \
            int src = b0 + 1; if (src == 3) src = 0;                            \
            convert(src, ((T) + 1) & 1);                                        \
        }                                                                       \
        lgkm0();                                                                \
        __builtin_amdgcn_sched_barrier(0);                                      \
        __builtin_amdgcn_s_barrier();                                           \
        if ((T) + 3 < NT) stage(b0, ((T) + 3) * 32);                            \
        _Pragma("unroll")                                                       \
        for (int nf = 0; nf < 4; ++nf) { bhf[nf] = bhn[nf]; blf[nf] = bln[nf]; }\
        b0 = b0 + 1; if (b0 == 3) b0 = 0;                                       \
    }

    for (int t = 0; t < NT - 2; ++t) G1D_BODY(t, 10);
    G1D_BODY(NT - 2, 8);
    G1D_BODY(NT - 1, 8);
#undef G1D_BODY

    // epilogue: LDS bounce per mf-slice -> fp16 convert -> 8B coalesced stores
    float* sc = (float*)smem;
    #pragma unroll
    for (int mf = 0; mf < 4; ++mf) {
        __syncthreads();
        #pragma unroll
        for (int nf = 0; nf < 4; ++nf)
            #pragma unroll
            for (int r = 0; r < 4; ++r) {
                const int rl = lk * 4 + r;
                const int col = col0 + nf * 16 + lm;
                sc[rl * M + (col ^ (lk << 3))] = acc[mf][nf][r];
            }
        __syncthreads();
        #pragma unroll
        for (int i = 0; i < 4; ++i) {
            const int idx = i * 256 + tid;
            const int rl = idx >> 6, u = idx & 63;
            const int grow = row0 + mf * 16 + rl;
            if (grow < N) {
                f32x4 v = *(const f32x4*)&sc[rl * M + ((u * 4) ^ (((rl >> 2) & 3) << 3))];
                half4v h;
                h[0] = (_Float16)v[0]; h[1] = (_Float16)v[1];
                h[2] = (_Float16)v[2]; h[3] = (_Float16)v[3];
                *(half4v*)&C16[(size_t)grow * M + u * 4] = h;
            }
        }
    }
}

// ---------------- GEMM (A pre-split bf16 h/l), counted-vmcnt 3-buf, fp16 out ----------------
template <int K, int NFW>
__global__ __launch_bounds__(256, 3)
void k_gemm_btc(const unsigned short* __restrict__ Ah, const unsigned short* __restrict__ Al,
                const unsigned short* __restrict__ Bh, const unsigned short* __restrict__ Bl,
                _Float16* __restrict__ C16, const int N) {
    constexpr int M = 64 * NFW;
    constexpr int NT = K / 32;
    constexpr int UPR = 16 * NFW;
    __shared__ char smem[24576];
    unsigned short* sAh = (unsigned short*)smem;          // [3][2048]
    unsigned short* sAl = sAh + 6144;                     // [3][2048]
    const int tid = threadIdx.x;
    const int lane = tid & 63;
    const int w = tid >> 6;
    const int lm = lane & 15, lk = lane >> 4;
    const int row0 = blockIdx.x * 64;
    const int col0 = w * (16 * NFW);

    const int kseg = (lane & 3) ^ ((lane >> 2) & 3);
    const int gr = min(row0 + w * 16 + (lane >> 2), N - 1);
    const size_t ga = (size_t)gr * K + kseg * 8;

    const int aoff = lm * 32 + ((lk ^ (lm & 3)) * 8);

    const unsigned short* bfh = Bh + ((size_t)(w * NFW) * NT) * 512 + lane * 8;
    const unsigned short* bfl = Bl + ((size_t)(w * NFW) * NT) * 512 + lane * 8;

    f32x4 acc[4][NFW];
    #pragma unroll
    for (int i = 0; i < 4; ++i)
        #pragma unroll
        for (int j = 0; j < NFW; ++j) acc[i][j] = (f32x4){0.f, 0.f, 0.f, 0.f};

    auto stage = [&](int bi, int kk) {
        __builtin_amdgcn_global_load_lds((const AS1 void*)(Ah + ga + kk),
                                         (AS3 void*)(sAh + bi * 2048 + w * 512), 16, 0, 0);
        __builtin_amdgcn_global_load_lds((const AS1 void*)(Al + ga + kk),
                                         (AS3 void*)(sAl + bi * 2048 + w * 512), 16, 0, 0);
    };

    stage(0, 0); stage(1, 32); stage(2, 64);

    short8 bhf[NFW], blf[NFW];
    #pragma unroll
    for (int nf = 0; nf < NFW; ++nf) {
        const size_t o = (size_t)nf * NT * 512;
        bhf[nf] = *(const short8*)(bfh + o);
        blf[nf] = *(const short8*)(bfl + o);
    }

    int bi = 0;

#define GBT_BODY(T, VM)                                                         \
    {                                                                           \
        vm_wait<VM>();                                                          \
        __builtin_amdgcn_s_barrier();                                           \
        __builtin_amdgcn_sched_barrier(0);                                      \
        short8 bhn[NFW], bln[NFW];                                              \
        _Pragma("unroll")                                                       \
        for (int nf = 0; nf < NFW; ++nf) { bhn[nf] = bhf[nf]; bln[nf] = blf[nf]; } \
        if ((T) + 1 < NT) {                                                     \
            _Pragma("unroll")                                                   \
            for (int nf = 0; nf < NFW; ++nf) {                                  \
                const size_t o = ((size_t)nf * NT + (T) + 1) * 512;             \
                bhn[nf] = *(const short8*)(bfh + o);                            \
                bln[nf] = *(const short8*)(bfl + o);                            \
            }                                                                   \
        }                                                                       \
        __builtin_amdgcn_sched_barrier(0);                                      \
        _Pragma("unroll")                                                       \
        for (int mf = 0; mf < 4; ++mf) {                                        \
            short8 ah = *(const short8*)&sAh[bi * 2048 + aoff + mf * 512];      \
            short8 al = *(const short8*)&sAl[bi * 2048 + aoff + mf * 512];      \
            _Pragma("unroll")                                                   \
            for (int nf = 0; nf < NFW; ++nf) {                                  \
                acc[mf][nf] = __builtin_amdgcn_mfma_f32_16x16x32_bf16(ah, bhf[nf], acc[mf][nf], 0, 0, 0); \
                acc[mf][nf] = __builtin_amdgcn_mfma_f32_16x16x32_bf16(ah, blf[nf], acc[mf][nf], 0, 0, 0); \
                acc[mf][nf] = __builtin_amdgcn_mfma_f32_16x16x32_bf16(al, bhf[nf], acc[mf][nf], 0, 0, 0); \
            }                                                                   \
        }                                                                       \
        lgkm0();                                                                \
        __builtin_amdgcn_sched_barrier(0);                                      \
        __builtin_amdgcn_s_barrier();                                           \
        if ((T) + 3 < NT) stage(bi, ((T) + 3) * 32);                            \
        _Pragma("unroll")                                                       \
        for (int nf = 0; nf < NFW; ++nf) { bhf[nf] = bhn[nf]; blf[nf] = bln[nf]; } \
        bi = bi + 1; if (bi == 3) bi = 0;                                       \
    }

    for (int t = 0; t < NT - 2; ++t) GBT_BODY(t, 2 * NFW + 4);
    GBT_BODY(NT - 2, 2 * NFW + 2);
    GBT_BODY(NT - 1, 2 * NFW);
#undef GBT_BODY

    float* sc = (float*)smem;
    #pragma unroll
    for (int mf = 0; mf < 4; ++mf) {
        __syncthreads();
        #pragma unroll
        for (int nf = 0; nf < NFW; ++nf)
            #pragma unroll
            for (int r = 0; r < 4; ++r) {
                const int rl = lk * 4 + r;
                const int col = col0 + nf * 16 + lm;
                sc[rl * M + (col ^ (lk << 3))] = acc[mf][nf][r];
            }
        __syncthreads();
        #pragma unroll
        for (int i = 0; i < (16 * UPR) / 256; ++i) {
            const int idx = i * 256 + tid;
            const int rl = idx / UPR, u = idx % UPR;
            const int grow = row0 + mf * 16 + rl;
            if (grow < N) {
                f32x4 v = *(const f32x4*)&sc[rl * M + ((u * 4) ^ (((rl >> 2) & 3) << 3))];
                half4v h;
                h[0] = (_Float16)v[0]; h[1] = (_Float16)v[1];
                h[2] = (_Float16)v[2]; h[3] = (_Float16)v[3];
                *(half4v*)&C16[(size_t)grow * M + u * 4] = h;
            }
        }
    }
}

// ---------------- SpMM on fp16 input (F=256), wave-per-row, fused bias+relu+split ----------------
__global__ __launch_bounds__(256)
void k_spmm256f(const int* __restrict__ rp, const int2* __restrict__ ev2,
                const _Float16* __restrict__ in16, const float* __restrict__ bias,
                unsigned short* __restrict__ oh, unsigned short* __restrict__ ol, int N) {
    const int lane = threadIdx.x & 63;
    int r = __builtin_amdgcn_readfirstlane(blockIdx.x * 4 + (threadIdx.x >> 6));
    if (r >= N) return;
    const int e0 = __builtin_amdgcn_readfirstlane(rp[r]);
    const int e1 = __builtin_amdgcn_readfirstlane(rp[r + 1]);
    f32x4 acc = {0.f, 0.f, 0.f, 0.f};
    const _Float16* base = in16 + lane * 4;

    #pragma unroll 4
    for (int e = e0; e < e1; ++e) {
        int2 p = ev2[e];
        half4v hv = *(const half4v*)(base + (size_t)p.x * 256);
        float val = __builtin_bit_cast(float, p.y);
        acc[0] = fmaf(val, (float)hv[0], acc[0]);
        acc[1] = fmaf(val, (float)hv[1], acc[1]);
        acc[2] = fmaf(val, (float)hv[2], acc[2]);
        acc[3] = fmaf(val, (float)hv[3], acc[3]);
    }

    f32x4 bv = *(const f32x4*)&bias[lane * 4];
    ushort4v h, l;
    #pragma unroll
    for (int j = 0; j < 4; ++j) {
        float o = fmaxf(acc[j] + bv[j], 0.f);
        unsigned short hh = f2bf_rne(o);
        h[j] = hh;
        l[j] = f2bf_rne(o - bf2f(hh));
    }
    *(ushort4v*)&oh[(size_t)r * 256 + lane * 4] = h;
    *(ushort4v*)&ol[(size_t)r * 256 + lane * 4] = l;
}

// ---------------- SpMM F=128 on fp16 input + fused bias/relu + final dense ----------------
__global__ __launch_bounds__(256)
void k_spmm128f(const int* __restrict__ rp, const int2* __restrict__ ev2,
                const _Float16* __restrict__ in16, const float* __restrict__ b3,
                const float* __restrict__ Wd, const float* __restrict__ bd,
                float* __restrict__ out, int N) {
    __shared__ float Ws[H4 * NCLASS];
    __shared__ float hrow[4][H4];
    {
        int i = threadIdx.x * 8;
        *(f32x4*)&Ws[i] = *(const f32x4*)&Wd[i];
        *(f32x4*)&Ws[i + 4] = *(const f32x4*)&Wd[i + 4];
    }
    __syncthreads();

    const int lane = threadIdx.x & 63;
    const int w = threadIdx.x >> 6;
    int r = __builtin_amdgcn_readfirstlane(blockIdx.x * 4 + w);
    if (r >= N) return;
    const int e0 = __builtin_amdgcn_readfirstlane(rp[r]);
    const int e1 = __builtin_amdgcn_readfirstlane(rp[r + 1]);
    float a0 = 0.f, a1 = 0.f;
    const _Float16* base = in16 + lane * 2;

    #pragma unroll 4
    for (int e = e0; e < e1; ++e) {
        int2 p = ev2[e];
        half2v hv = *(const half2v*)(base + (size_t)p.x * 128);
        float v = __builtin_bit_cast(float, p.y);
        a0 = fmaf(v, (float)hv[0], a0);
        a1 = fmaf(v, (float)hv[1], a1);
    }

    float2 hb;
    hb.x = fmaxf(a0 + b3[lane * 2 + 0], 0.f);
    hb.y = fmaxf(a1 + b3[lane * 2 + 1], 0.f);
    *(float2*)&hrow[w][lane * 2] = hb;

    const int c = lane & 15, q = lane >> 4;
    float s = 0.f;
    #pragma unroll
    for (int k = q * 32; k < q * 32 + 32; ++k)
        s = fmaf(hrow[w][k], Ws[k * NCLASS + c], s);
    s += __shfl_xor(s, 16);
    s += __shfl_xor(s, 32);
    if (lane < 16) out[(size_t)r * NCLASS + lane] = s + bd[lane];
}

extern "C" void kernel_launch(void* const* d_in, const int* in_sizes, int n_in,
                              void* d_out, int out_size, void* d_ws, size_t ws_size,
                              hipStream_t stream) {
    const float* x  = (const float*)d_in[0];
    const int*   er = (const int*)d_in[1];
    const int*   ec = (const int*)d_in[2];
    const float* ev = (const float*)d_in[3];
    const float* W1 = (const float*)d_in[4];
    const float* b1 = (const float*)d_in[5];
    const float* W2 = (const float*)d_in[6];
    const float* b2 = (const float*)d_in[7];
    const float* W3 = (const float*)d_in[8];
    const float* b3 = (const float*)d_in[9];
    const float* Wd = (const float*)d_in[10];
    const float* bd = (const float*)d_in[11];
    float* out = (float*)d_out;

    const int N = in_sizes[0] / NFEAT;
    const int E = in_sizes[1];

    char* w = (char*)d_ws;
    auto alloc = [&](size_t bytes) { char* p = w; w += (bytes + 255) & ~(size_t)255; return p; };
    _Float16* C16 = (_Float16*)alloc((size_t)N * 256 * 2);
    unsigned short* hh = (unsigned short*)alloc((size_t)N * 256 * 2);
    unsigned short* hl = (unsigned short*)alloc((size_t)N * 256 * 2);
    int* cnt  = (int*)alloc((size_t)N * 4);
    int* rp   = (int*)alloc((size_t)(N + 1) * 4);
    int* ofs  = (int*)alloc((size_t)N * 4);
    int2* ev2 = (int2*)alloc((size_t)E * 8);
    int* bsum = (int*)alloc(4096);
    unsigned short* W1h = (unsigned short*)alloc((size_t)NFEAT * H2 * 2);
    unsigned short* W1l = (unsigned short*)alloc((size_t)NFEAT * H2 * 2);
    unsigned short* W2h = (unsigned short*)alloc((size_t)H2 * H3 * 2);
    unsigned short* W2l = (unsigned short*)alloc((size_t)H2 * H3 * 2);
    unsigned short* W3h = (unsigned short*)alloc((size_t)H3 * H4 * 2);
    unsigned short* W3l = (unsigned short*)alloc((size_t)H3 * H4 * 2);

    const int nb = (N + 255) / 256;
    const int sliceSz = (N + 7) / 8;

    hipMemsetAsync(cnt, 0, (size_t)N * 4, stream);
    k_hist<<<1024, 256, 0, stream>>>(er, cnt, E);
    k_scan1<<<nb, 256, 0, stream>>>(cnt, rp, bsum, N);
    k_scan2<<<1, 512, 0, stream>>>(bsum, nb);
    k_scan3<<<nb, 256, 0, stream>>>(rp, ofs, bsum, cnt, N);
    k_scatter_sl<<<2048, 256, 0, stream>>>(er, ec, ev, ofs, ev2, E, sliceSz);

    k_packb<<<(NFEAT * H2 / 8 + 255) / 256, 256, 0, stream>>>(W1, W1h, W1l, NFEAT, H2);
    k_packb<<<(H2 * H3 / 8 + 255) / 256, 256, 0, stream>>>(W2, W2h, W2l, H2, H3);
    k_packb<<<(H3 * H4 / 8 + 255) / 256, 256, 0, stream>>>(W3, W3h, W3l, H3, H4);

    const int rgrid = (N + 63) / 64;
    const int sgrid = (N + 3) / 4;

    k_gemm1d<<<rgrid, 256, 0, stream>>>(x, W1h, W1l, C16, N);
    k_spmm256f<<<sgrid, 256, 0, stream>>>(rp, ev2, C16, b1, hh, hl, N);

    k_gemm_btc<H2, 4><<<rgrid, 256, 0, stream>>>(hh, hl, W2h, W2l, C16, N);
    k_spmm256f<<<sgrid, 256, 0, stream>>>(rp, ev2, C16, b2, hh, hl, N);

    k_gemm_btc<H3, 2><<<rgrid, 256, 0, stream>>>(hh, hl, W3h, W3l, C16, N);
    k_spmm128f<<<sgrid, 256, 0, stream>>>(rp, ev2, C16, b3, Wd, bd, out, N);
}